// Round 2
// 202.293 us; speedup vs baseline: 1.1774x; 1.1774x over previous
//
#include <hip/hip_runtime.h>
#include <hip/hip_fp16.h>
#include <stdint.h>

typedef float f4 __attribute__((ext_vector_type(4)));
typedef float f32x4 __attribute__((ext_vector_type(4)));
typedef _Float16 f16x8 __attribute__((ext_vector_type(8)));

#define BSHIFT 8
#define BMASK  255
#define BCAP   8192   // edges per 256-node bucket (mean 4096, sigma 64 -> 64-sigma headroom)

// ---------- bin: edges -> per-bucket regions, packed (row<<8 | node_in_bucket) ----------
// 4096 edges/block; LDS histogram; one global atomic per (block,bucket) chunk.
// Last 2 blocks instead build Wt1/Wt2 = fp16 transposed weights for the MFMA GEMM.
__global__ __launch_bounds__(256) void bin_kernel(const int* __restrict__ row,
                                                  const int* __restrict__ col,
                                                  int* __restrict__ gcur,
                                                  uint32_t* __restrict__ binned,
                                                  int E, int n, int nbuck,
                                                  const float* __restrict__ W1,
                                                  const float* __restrict__ W2,
                                                  __half* __restrict__ Wt1,
                                                  __half* __restrict__ Wt2) {
    __shared__ int hist[256];
    __shared__ int base[256];
    int t = threadIdx.x;
    int nbin = gridDim.x - 2;
    if (blockIdx.x >= nbin) {
        // transpose W (128x128 f32 row-major [k][c]) -> Wt fp16 [c][k]
        int wi = blockIdx.x - nbin;
        const f4* w4 = (const f4*)(wi ? W2 : W1);
        _Float16* dst = (_Float16*)(wi ? Wt2 : Wt1);
#pragma unroll
        for (int i = 0; i < 16; ++i) {
            int chunk = i * 256 + t;          // 4096 f4 chunks
            f4 v = w4[chunk];
            int b4 = chunk * 4;
            int k = b4 >> 7, c0 = b4 & 127;
#pragma unroll
            for (int u = 0; u < 4; ++u)
                dst[(size_t)(c0 + u) * 128 + k] = (_Float16)v[u];
        }
        return;
    }
    hist[t] = 0;
    __syncthreads();
    int e0 = blockIdx.x * 4096 + t;
    int cc[16]; uint32_t pk[16];
#pragma unroll
    for (int i = 0; i < 16; ++i) {
        int e = e0 + i * 256;
        cc[i] = -1; pk[i] = 0;
        if (e < E) {
            int c = col[e];
            if ((unsigned)c < (unsigned)n) {
                cc[i] = c >> BSHIFT;                                  // bucket id
                pk[i] = ((uint32_t)row[e] << BSHIFT) | (uint32_t)(c & BMASK);
            }
        }
    }
#pragma unroll
    for (int i = 0; i < 16; ++i)
        if (cc[i] >= 0) atomicAdd(&hist[cc[i]], 1);
    __syncthreads();
    if (t < nbuck) {
        base[t] = atomicAdd(&gcur[t], hist[t]);
        hist[t] = 0;
    }
    __syncthreads();
#pragma unroll
    for (int i = 0; i < 16; ++i)
        if (cc[i] >= 0) {
            int b = cc[i];
            int p = base[b] + atomicAdd(&hist[b], 1);
            if (p < BCAP) binned[(size_t)b * BCAP + p] = pk[i];
        }
}

// ---------- bucket: per 256-node bucket -> off / dinv / csr ----------
__global__ __launch_bounds__(256) void bucket_kernel(const uint32_t* __restrict__ binned,
                                                     const int* __restrict__ gcur,
                                                     int* __restrict__ off,
                                                     float* __restrict__ dinv,
                                                     int* __restrict__ csr,
                                                     int n, int nbuck) {
    __shared__ int wtot[4];
    __shared__ int sbase[256];
    __shared__ int hist[256];
    __shared__ int cur[256];
    int t = threadIdx.x;
    int lane = t & 63, w = t >> 6;
    int b = blockIdx.x;

    // exclusive prefix over the bucket counts (every block redoes it; L2-hot)
    int v = (t < nbuck) ? gcur[t] : 0;
    int inc = v;
#pragma unroll
    for (int d = 1; d < 64; d <<= 1) { int u = __shfl_up(inc, d); if (lane >= d) inc += u; }
    if (lane == 63) wtot[w] = inc;
    __syncthreads();
    int wb = 0;
    for (int i = 0; i < w; ++i) wb += wtot[i];
    sbase[t] = wb + inc - v;          // exclusive prefix of bucket counts
    __syncthreads();
    int base_b = sbase[b];
    int c_b    = gcur[b];

    // local degree histogram
    hist[t] = 0;
    __syncthreads();
    const uint32_t* reg = binned + (size_t)b * BCAP;
    for (int j = t; j < c_b; j += 256)
        atomicAdd(&hist[reg[j] & BMASK], 1);
    __syncthreads();
    int h = hist[t];

    // local exclusive scan of degrees
    int inc2 = h;
#pragma unroll
    for (int d = 1; d < 64; d <<= 1) { int u = __shfl_up(inc2, d); if (lane >= d) inc2 += u; }
    __syncthreads();                  // wtot reuse barrier
    if (lane == 63) wtot[w] = inc2;
    __syncthreads();
    int wb2 = 0;
    for (int i = 0; i < w; ++i) wb2 += wtot[i];
    int lo = wb2 + inc2 - h;          // exclusive local offset

    int node = (b << BSHIFT) + t;
    if (node < n) {
        off[node]  = base_b + lo;
        dinv[node] = rsqrtf((float)(h + 1));   // +1: the self-loop
    }
    if (b == nbuck - 1 && t == 0)
        off[n] = sbase[nbuck - 1] + gcur[nbuck - 1];

    cur[t] = base_b + lo;
    __syncthreads();
    for (int j = t; j < c_b; j += 256) {
        uint32_t pv = reg[j];
        int p = atomicAdd(&cur[pv & BMASK], 1);
        csr[p] = (int)(pv >> BSHIFT);
    }
}

// ---------- GEMM (MFMA): g16[row] = half(dinv[row] * (src[row] @ W)) ----------
// Block = 64 rows x 128 cols, 4 waves, wave owns 16 rows. A split-precision:
// x = hi + lo (both fp16), h = hi@W + lo@W with fp32 MFMA accumulate -> A-input
// rounding eliminated; only W fp16 rounding (~2e-4) remains. A (hi+lo) and
// B (Wt fp16 [col][k]) staged in LDS with XOR swizzle byte^=((row&7)<<4).
// In-place over src safe: block's src rows all staged to LDS before any store.
__global__ __launch_bounds__(256) void gemm_mfma(const float* __restrict__ src,
                                                 const __half* __restrict__ Wt,
                                                 const float* __restrict__ dinv,
                                                 __half* __restrict__ g16, int nrows) {
    __shared__ _Float16 Ahi[64 * 128];    // 16 KB
    __shared__ _Float16 Alo[64 * 128];    // 16 KB
    __shared__ _Float16 Bsw[128 * 128];   // 32 KB
    int t = threadIdx.x;
    int row0 = blockIdx.x * 64;

    // stage B: 2048 16B chunks of Wt [c][k]
    {
        const f4* wsrc = (const f4*)Wt;
#pragma unroll
        for (int i = 0; i < 8; ++i) {
            int cb = i * 256 + t;
            f4 v = wsrc[cb];
            int lin = cb * 16;
            int c = cb >> 4;
            *(f4*)((char*)Bsw + (lin ^ ((c & 7) << 4))) = v;
        }
    }
    // stage A: 1024 16B chunks; fp32 -> fp16 hi + fp16 residual on the fly
    {
#pragma unroll
        for (int i = 0; i < 4; ++i) {
            int c = i * 256 + t;
            int r = c >> 4, kc = c & 15;
            int rg = row0 + r; if (rg >= nrows) rg = nrows - 1;
            const f4* xr = (const f4*)(src + (size_t)rg * 128);
            f4 v0 = xr[kc * 2], v1 = xr[kc * 2 + 1];
            f16x8 hv, lv;
#pragma unroll
            for (int u = 0; u < 4; ++u) {
                float a0 = v0[u]; _Float16 h0 = (_Float16)a0;
                hv[u] = h0;     lv[u]     = (_Float16)(a0 - (float)h0);
                float a1 = v1[u]; _Float16 h1 = (_Float16)a1;
                hv[u + 4] = h1; lv[u + 4] = (_Float16)(a1 - (float)h1);
            }
            int lin = c * 16;
            int sw = (r & 7) << 4;
            *(f16x8*)((char*)Ahi + (lin ^ sw)) = hv;
            *(f16x8*)((char*)Alo + (lin ^ sw)) = lv;
        }
    }
    __syncthreads();

    int w = t >> 6, lane = t & 63;
    int li = lane & 15, hg = lane >> 4;

    // A frags: row = w*16 + li, k = kk*32 + hg*8 .. +7  (reused across all 8 col-tiles)
    f16x8 af[4], al[4];
    {
        int r = w * 16 + li;
        int rbase = r * 256;
        int sw = (r & 7) << 4;
#pragma unroll
        for (int kk = 0; kk < 4; ++kk) {
            int o = (rbase + kk * 64 + hg * 16) ^ sw;
            af[kk] = *(const f16x8*)((const char*)Ahi + o);
            al[kk] = *(const f16x8*)((const char*)Alo + o);
        }
    }

    f32x4 acc[8];
#pragma unroll
    for (int nn = 0; nn < 8; ++nn) acc[nn] = (f32x4)0.0f;

#pragma unroll
    for (int nn = 0; nn < 8; ++nn) {
        int c = nn * 16 + li;
        int cbase = c * 256;
        int sw = (c & 7) << 4;
#pragma unroll
        for (int kk = 0; kk < 4; ++kk) {
            f16x8 bf = *(const f16x8*)((const char*)Bsw + ((cbase + kk * 64 + hg * 16) ^ sw));
            acc[nn] = __builtin_amdgcn_mfma_f32_16x16x32_f16(af[kk], bf, acc[nn], 0, 0, 0);
            acc[nn] = __builtin_amdgcn_mfma_f32_16x16x32_f16(al[kk], bf, acc[nn], 0, 0, 0);
        }
    }

    // epilogue: C/D layout col = lane&15, row = (lane>>4)*4 + reg  (m89, dtype-independent)
    int gr0 = row0 + w * 16 + (hg << 2);
    float dv[4];
#pragma unroll
    for (int q = 0; q < 4; ++q) {
        int rr = gr0 + q;
        dv[q] = dinv[rr < nrows ? rr : 0];
    }
#pragma unroll
    for (int nn = 0; nn < 8; ++nn) {
        int c = nn * 16 + li;
#pragma unroll
        for (int q = 0; q < 4; ++q) {
            int rr = gr0 + q;
            if (rr < nrows)
                g16[(size_t)rr * 256 + c] = __float2half(acc[nn][q] * dv[q]);
        }
    }
}

// ---------- aggregation: one wave per node, 4x 16-lane groups, 4 edges in flight ----------
// Lane (g = lane>>4, li = lane&15) loads 16B (8 cols) of edge t+g's row -> one
// dwordx4 gather instruction covers 4 edges. Cross-group reduce via shfl_xor 16/32.
__global__ __launch_bounds__(256) void agg_f16(const __half* __restrict__ gh,   // 512-B slots
                                               const int* __restrict__ csr,
                                               const int* __restrict__ off,
                                               const float* __restrict__ dinv,
                                               const f4* __restrict__ bias4,    // [32]
                                               f4* __restrict__ out4,           // [N*32]
                                               int n) {
    int wid  = (blockIdx.x * 256 + threadIdx.x) >> 6;
    int lane = threadIdx.x & 63;
    if (wid >= n) return;
    int g  = lane >> 4;
    int li = lane & 15;

    float a[8];
    {
        f4 sv = ((const f4*)(gh + (size_t)wid * 256))[li];   // self row (counted once, by g==0)
        __half2* sh = (__half2*)&sv;
        if (g == 0) {
#pragma unroll
            for (int i = 0; i < 4; ++i) { float2 f = __half22float2(sh[i]); a[2*i] = f.x; a[2*i+1] = f.y; }
        } else {
#pragma unroll
            for (int j = 0; j < 8; ++j) a[j] = 0.0f;
        }
    }

    int s = off[wid], e = off[wid + 1];
    for (int base = s; base < e; base += 64) {
        int idx = 0;
        if (base + lane < e) idx = csr[base + lane];          // one coalesced load / 64 edges
        int cnt = e - base; if (cnt > 64) cnt = 64;
        int t = 0;
        for (; t + 8 <= cnt; t += 8) {
            int r0 = __shfl(idx, t + g);
            int r1 = __shfl(idx, t + 4 + g);
            f4 v0 = ((const f4*)(gh + (size_t)r0 * 256))[li];
            f4 v1 = ((const f4*)(gh + (size_t)r1 * 256))[li];
            __half2* h0 = (__half2*)&v0;
            __half2* h1 = (__half2*)&v1;
#pragma unroll
            for (int i = 0; i < 4; ++i) {
                float2 f0 = __half22float2(h0[i]);
                float2 f1 = __half22float2(h1[i]);
                a[2*i]   += f0.x + f1.x;
                a[2*i+1] += f0.y + f1.y;
            }
        }
        for (; t < cnt; t += 4) {
            int tg = t + g;
            int r = __shfl(idx, tg < 64 ? tg : 0);            // convergent shfl
            if (tg < cnt) {
                f4 v = ((const f4*)(gh + (size_t)r * 256))[li];
                __half2* hv = (__half2*)&v;
#pragma unroll
                for (int i = 0; i < 4; ++i) {
                    float2 f = __half22float2(hv[i]);
                    a[2*i] += f.x; a[2*i+1] += f.y;
                }
            }
        }
    }

#pragma unroll
    for (int j = 0; j < 8; ++j) {
        a[j] += __shfl_xor(a[j], 16);
        a[j] += __shfl_xor(a[j], 32);
    }
    if (g == 0) {
        float di = dinv[wid];
        f4 b0 = bias4[li * 2], b1v = bias4[li * 2 + 1];
        f4 o0, o1;
#pragma unroll
        for (int u = 0; u < 4; ++u) {
            o0[u] = fmaxf(fmaf(di, a[u],     b0[u]),  0.0f);
            o1[u] = fmaxf(fmaf(di, a[4 + u], b1v[u]), 0.0f);
        }
        // 128-float row = 32 f4 slots (was the round-1 bug: stride 8)
        out4[(size_t)wid * 32 + li * 2]     = o0;
        out4[(size_t)wid * 32 + li * 2 + 1] = o1;
    }
}

// ---------- launch ----------
extern "C" void kernel_launch(void* const* d_in, const int* in_sizes, int n_in,
                              void* d_out, int out_size, void* d_ws, size_t ws_size,
                              hipStream_t stream) {
    float*       xbuf = (float*)d_in[0];        // fp32 input; reused as slotted fp16 g-table
    const int*   ei   = (const int*)d_in[1];
    const float* W1   = (const float*)d_in[2];
    const float* b1   = (const float*)d_in[3];
    const float* W2   = (const float*)d_in[4];
    const float* b2   = (const float*)d_in[5];
    float*       out  = (float*)d_out;

    int N = in_sizes[0] / 128;
    int E = in_sizes[1] / 2;
    const int* row = ei;          // sources (x_j)
    const int* col = ei + E;      // targets (aggregate index)

    int nbuck = (N + 255) >> BSHIFT;   // 196 for N=50000

    auto align256 = [](size_t v) { return (v + 255) & ~(size_t)255; };
    char* ws = (char*)d_ws;
    size_t pos = 0;
    int*      off    = (int*)(ws + pos);      pos += align256((size_t)(N + 1) * 4);
    float*    dinv   = (float*)(ws + pos);    pos += align256((size_t)N * 4);
    int*      csr    = (int*)(ws + pos);      pos += align256((size_t)E * 4);
    int*      gcur   = (int*)(ws + pos);      pos += align256(256 * 4);
    uint32_t* binned = (uint32_t*)(ws + pos); pos += align256((size_t)nbuck * BCAP * 4);
    __half*   Wt1    = (__half*)(ws + pos);   pos += align256(128 * 128 * 2);
    __half*   Wt2    = (__half*)(ws + pos);   pos += align256(128 * 128 * 2);
    // total ~10 MB

    __half* g16 = (__half*)xbuf;   // 512-B slots overlaying the fp32 rows

    int binblocks = (E + 4095) / 4096;
    int gblocks   = (N + 63) / 64;
    int ablocks   = (N + 3) / 4;

    hipMemsetAsync(gcur, 0, 256 * 4, stream);
    bin_kernel<<<binblocks + 2, 256, 0, stream>>>(row, col, gcur, binned, E, N, nbuck,
                                                  W1, W2, Wt1, Wt2);
    bucket_kernel<<<nbuck, 256, 0, stream>>>(binned, gcur, off, dinv, csr, N, nbuck);

    // layer 1: g1 = fp16(dinv * (x @ W1)) in-place slots; act1 = relu(di*Σg + b1) -> d_out
    gemm_mfma<<<gblocks, 256, 0, stream>>>(xbuf, Wt1, dinv, g16, N);
    agg_f16<<<ablocks, 256, 0, stream>>>(g16, csr, off, dinv, (const f4*)b1, (f4*)out, N);
    // layer 2: g2 = fp16(dinv * (act1 @ W2)) -> same slots; out = relu(di*Σg + b2) -> d_out
    gemm_mfma<<<gblocks, 256, 0, stream>>>(out, Wt2, dinv, g16, N);
    agg_f16<<<ablocks, 256, 0, stream>>>(g16, csr, off, dinv, (const f4*)b2, (f4*)out, N);
}

// Round 3
// 197.748 us; speedup vs baseline: 1.2045x; 1.0230x over previous
//
#include <hip/hip_runtime.h>
#include <hip/hip_fp16.h>
#include <stdint.h>

typedef float f4 __attribute__((ext_vector_type(4)));
typedef float f32x4 __attribute__((ext_vector_type(4)));
typedef _Float16 f16x8 __attribute__((ext_vector_type(8)));

#define BSHIFT 8
#define BMASK  255
#define BCAP   8192   // edges per 256-node bucket (mean 4096 -> huge headroom)

// ---------- prep: zero gcur + transpose W1/W2 -> fp16 [c][k] (replaces memset) ----------
__global__ __launch_bounds__(256) void prep_kernel(const float* __restrict__ W1,
                                                   const float* __restrict__ W2,
                                                   __half* __restrict__ Wt1,
                                                   __half* __restrict__ Wt2,
                                                   int* __restrict__ gcur) {
    int t = threadIdx.x, b = blockIdx.x;
    if (b == 0) { gcur[t] = 0; return; }
    int wi = (b - 1) >> 3, bi = (b - 1) & 7;
    const f4* w4 = (const f4*)(wi ? W2 : W1);
    _Float16* dst = (_Float16*)(wi ? Wt2 : Wt1);
#pragma unroll
    for (int it = 0; it < 2; ++it) {
        int chunk = bi * 512 + it * 256 + t;      // f4 index into 128x128 W
        f4 v = w4[chunk];
        int k = chunk >> 5, c0 = (chunk << 2) & 127;
#pragma unroll
        for (int u = 0; u < 4; ++u)
            dst[(size_t)(c0 + u) * 128 + k] = (_Float16)v[u];
    }
}

// ---------- gemm body: g16[row] = half(src[row] @ W)  (NO dinv — deferred to agg) ----------
// Block = 64 rows x 128 cols, 4 waves. A split-precision hi+lo fp16 (A-rounding
// eliminated), B = Wt fp16 [c][k]. XOR swizzle byte^=((row&7)<<4) on LDS tiles.
// In-place over src safe: block stages all its rows to LDS before any store.
__device__ __forceinline__ void gemm_body(char* smem, int blk,
                                          const float* __restrict__ src,
                                          const __half* __restrict__ Wt,
                                          __half* __restrict__ g16, int nrows) {
    _Float16* Ahi = (_Float16*)smem;              // 16 KB
    _Float16* Alo = (_Float16*)(smem + 16384);    // 16 KB
    _Float16* Bsw = (_Float16*)(smem + 32768);    // 32 KB
    int t = threadIdx.x;
    int row0 = blk * 64;

    {   // stage B: 2048 16B chunks of Wt [c][k]
        const f4* wsrc = (const f4*)Wt;
#pragma unroll
        for (int i = 0; i < 8; ++i) {
            int cb = i * 256 + t;
            f4 v = wsrc[cb];
            int lin = cb * 16;
            int c = cb >> 4;
            *(f4*)((char*)Bsw + (lin ^ ((c & 7) << 4))) = v;
        }
    }
    {   // stage A: fp32 -> fp16 hi + fp16 residual
#pragma unroll
        for (int i = 0; i < 4; ++i) {
            int c = i * 256 + t;
            int r = c >> 4, kc = c & 15;
            int rg = row0 + r; if (rg >= nrows) rg = nrows - 1;
            const f4* xr = (const f4*)(src + (size_t)rg * 128);
            f4 v0 = xr[kc * 2], v1 = xr[kc * 2 + 1];
            f16x8 hv, lv;
#pragma unroll
            for (int u = 0; u < 4; ++u) {
                float a0 = v0[u]; _Float16 h0 = (_Float16)a0;
                hv[u] = h0;     lv[u]     = (_Float16)(a0 - (float)h0);
                float a1 = v1[u]; _Float16 h1 = (_Float16)a1;
                hv[u + 4] = h1; lv[u + 4] = (_Float16)(a1 - (float)h1);
            }
            int lin = c * 16;
            int sw = (r & 7) << 4;
            *(f16x8*)((char*)Ahi + (lin ^ sw)) = hv;
            *(f16x8*)((char*)Alo + (lin ^ sw)) = lv;
        }
    }
    __syncthreads();

    int w = t >> 6, lane = t & 63;
    int li = lane & 15, hg = lane >> 4;

    f16x8 af[4], al[4];
    {
        int r = w * 16 + li;
        int rbase = r * 256;
        int sw = (r & 7) << 4;
#pragma unroll
        for (int kk = 0; kk < 4; ++kk) {
            int o = (rbase + kk * 64 + hg * 16) ^ sw;
            af[kk] = *(const f16x8*)((const char*)Ahi + o);
            al[kk] = *(const f16x8*)((const char*)Alo + o);
        }
    }

    f32x4 acc[8];
#pragma unroll
    for (int nn = 0; nn < 8; ++nn) acc[nn] = (f32x4)0.0f;

#pragma unroll
    for (int nn = 0; nn < 8; ++nn) {
        int c = nn * 16 + li;
        int cbase = c * 256;
        int sw = (c & 7) << 4;
#pragma unroll
        for (int kk = 0; kk < 4; ++kk) {
            f16x8 bf = *(const f16x8*)((const char*)Bsw + ((cbase + kk * 64 + hg * 16) ^ sw));
            acc[nn] = __builtin_amdgcn_mfma_f32_16x16x32_f16(af[kk], bf, acc[nn], 0, 0, 0);
            acc[nn] = __builtin_amdgcn_mfma_f32_16x16x32_f16(al[kk], bf, acc[nn], 0, 0, 0);
        }
    }

    // epilogue: C/D col = lane&15, row = (lane>>4)*4 + reg (m89)
    int gr0 = row0 + w * 16 + (hg << 2);
#pragma unroll
    for (int nn = 0; nn < 8; ++nn) {
        int c = nn * 16 + li;
#pragma unroll
        for (int q = 0; q < 4; ++q) {
            int rr = gr0 + q;
            if (rr < nrows)
                g16[(size_t)rr * 256 + c] = __float2half(acc[nn][q]);
        }
    }
}

// ---------- bin body: 1024 edges/block -> packed (row<<8 | node_in_bucket) ----------
__device__ __forceinline__ void bin_body(char* smem, int bb,
                                         const int* __restrict__ row,
                                         const int* __restrict__ col,
                                         int* __restrict__ gcur,
                                         uint32_t* __restrict__ binned,
                                         int E, int n, int nbuck) {
    int* hist = (int*)smem;
    int* base = (int*)(smem + 1024);
    int t = threadIdx.x;
    hist[t] = 0;
    __syncthreads();
    int e0 = bb * 1024 + t;
    int cc[4]; uint32_t pk[4];
#pragma unroll
    for (int i = 0; i < 4; ++i) {
        int e = e0 + i * 256;
        cc[i] = -1; pk[i] = 0;
        if (e < E) {
            int c = col[e];
            if ((unsigned)c < (unsigned)n) {
                cc[i] = c >> BSHIFT;
                pk[i] = ((uint32_t)row[e] << BSHIFT) | (uint32_t)(c & BMASK);
            }
        }
    }
#pragma unroll
    for (int i = 0; i < 4; ++i)
        if (cc[i] >= 0) atomicAdd(&hist[cc[i]], 1);
    __syncthreads();
    if (t < nbuck) {
        int h = hist[t];
        if (h) base[t] = atomicAdd(&gcur[t], h);
        hist[t] = 0;
    }
    __syncthreads();
#pragma unroll
    for (int i = 0; i < 4; ++i)
        if (cc[i] >= 0) {
            int b = cc[i];
            int p = base[b] + atomicAdd(&hist[b], 1);
            if (p < BCAP) binned[(size_t)b * BCAP + p] = pk[i];
        }
}

// ---------- fused kernel1: gemm1 blocks + bin blocks (disjoint roles) ----------
__global__ __launch_bounds__(256) void gemm_bin_kernel(const float* __restrict__ src,
                                                       const __half* __restrict__ Wt,
                                                       __half* __restrict__ g16,
                                                       int nrows, int gblocks,
                                                       const int* __restrict__ row,
                                                       const int* __restrict__ col,
                                                       int* __restrict__ gcur,
                                                       uint32_t* __restrict__ binned,
                                                       int E, int n, int nbuck) {
    __shared__ char smem[65536];
    if ((int)blockIdx.x < gblocks)
        gemm_body(smem, blockIdx.x, src, Wt, g16, nrows);
    else
        bin_body(smem, blockIdx.x - gblocks, row, col, gcur, binned, E, n, nbuck);
}

// ---------- bucket: 1024 threads/block, per 256-node bucket -> off / dinv / csr ----------
__global__ __launch_bounds__(1024) void bucket_kernel(const uint32_t* __restrict__ binned,
                                                      const int* __restrict__ gcur,
                                                      int* __restrict__ off,
                                                      float* __restrict__ dinv,
                                                      int* __restrict__ csr,
                                                      int n, int nbuck) {
    __shared__ int wtot[4];
    __shared__ int sbase[256];
    __shared__ int hist[256];
    __shared__ int cur[256];
    int t = threadIdx.x;
    int lane = t & 63, w = t >> 6;
    int b = blockIdx.x;

    // exclusive prefix over bucket counts (threads < 256 = waves 0..3)
    int v = 0, inc = 0;
    if (t < 256) {
        v = (t < nbuck) ? gcur[t] : 0;
        inc = v;
#pragma unroll
        for (int d = 1; d < 64; d <<= 1) { int u = __shfl_up(inc, d); if (lane >= d) inc += u; }
        if (lane == 63) wtot[w] = inc;
    }
    __syncthreads();
    if (t < 256) {
        int wb = 0;
        for (int i = 0; i < w; ++i) wb += wtot[i];
        sbase[t] = wb + inc - v;
    }
    __syncthreads();
    int base_b = sbase[b];
    int c_b    = gcur[b];

    if (t < 256) hist[t] = 0;
    __syncthreads();
    const uint32_t* reg = binned + (size_t)b * BCAP;
    for (int j = t; j < c_b; j += 1024)
        atomicAdd(&hist[reg[j] & BMASK], 1);
    __syncthreads();

    int h = 0, inc2 = 0;
    if (t < 256) {
        h = hist[t];
        inc2 = h;
#pragma unroll
        for (int d = 1; d < 64; d <<= 1) { int u = __shfl_up(inc2, d); if (lane >= d) inc2 += u; }
        if (lane == 63) wtot[w] = inc2;
    }
    __syncthreads();
    if (t < 256) {
        int wb2 = 0;
        for (int i = 0; i < w; ++i) wb2 += wtot[i];
        int lo = wb2 + inc2 - h;
        int node = (b << BSHIFT) + t;
        if (node < n) {
            off[node]  = base_b + lo;
            dinv[node] = rsqrtf((float)(h + 1));   // +1: self-loop
        }
        cur[t] = base_b + lo;
    }
    if (b == nbuck - 1 && t == 0)
        off[n] = sbase[nbuck - 1] + gcur[nbuck - 1];
    __syncthreads();
    for (int j = t; j < c_b; j += 1024) {
        uint32_t pv = reg[j];
        int p = atomicAdd(&cur[pv & BMASK], 1);
        csr[p] = (int)(pv >> BSHIFT);
    }
}

// ---------- aggregation: wave/node, 4x16-lane groups; per-edge dinv via gathered dv ----------
// out[i] = relu( di*( di*h_self + Σ_e dv_e*h_e ) + b )
__global__ __launch_bounds__(256) void agg_f16(const __half* __restrict__ gh,   // 512-B slots
                                               const int* __restrict__ csr,
                                               const int* __restrict__ off,
                                               const float* __restrict__ dinv,
                                               const f4* __restrict__ bias4,    // [32]
                                               f4* __restrict__ out4,           // [N*32]
                                               int n) {
    int wid  = (blockIdx.x * 256 + threadIdx.x) >> 6;
    int lane = threadIdx.x & 63;
    if (wid >= n) return;
    int g  = lane >> 4;
    int li = lane & 15;
    float di = dinv[wid];

    float a[8];
    {
        f4 sv = ((const f4*)(gh + (size_t)wid * 256))[li];   // self row (g==0 only)
        __half2* sh = (__half2*)&sv;
        if (g == 0) {
#pragma unroll
            for (int i = 0; i < 4; ++i) {
                float2 f = __half22float2(sh[i]);
                a[2*i] = di * f.x; a[2*i+1] = di * f.y;
            }
        } else {
#pragma unroll
            for (int j = 0; j < 8; ++j) a[j] = 0.0f;
        }
    }

    int s = off[wid], e = off[wid + 1];
    for (int base = s; base < e; base += 64) {
        int idx = 0; float dv = 0.0f;
        if (base + lane < e) {
            idx = csr[base + lane];          // coalesced
            dv  = dinv[idx];                 // 4B gather
        }
        int cnt = e - base; if (cnt > 64) cnt = 64;
        int t = 0;
        for (; t + 16 <= cnt; t += 16) {     // 16 edges, 4 gathers in flight/lane
            int r0 = __shfl(idx, t + g),      r1 = __shfl(idx, t + 4 + g);
            int r2 = __shfl(idx, t + 8 + g),  r3 = __shfl(idx, t + 12 + g);
            float d0 = __shfl(dv, t + g),     d1 = __shfl(dv, t + 4 + g);
            float d2 = __shfl(dv, t + 8 + g), d3 = __shfl(dv, t + 12 + g);
            f4 v0 = ((const f4*)(gh + (size_t)r0 * 256))[li];
            f4 v1 = ((const f4*)(gh + (size_t)r1 * 256))[li];
            f4 v2 = ((const f4*)(gh + (size_t)r2 * 256))[li];
            f4 v3 = ((const f4*)(gh + (size_t)r3 * 256))[li];
            __half2* h0 = (__half2*)&v0; __half2* h1 = (__half2*)&v1;
            __half2* h2 = (__half2*)&v2; __half2* h3 = (__half2*)&v3;
#pragma unroll
            for (int i = 0; i < 4; ++i) {
                float2 f0 = __half22float2(h0[i]); float2 f1 = __half22float2(h1[i]);
                float2 f2 = __half22float2(h2[i]); float2 f3 = __half22float2(h3[i]);
                a[2*i]   = fmaf(d0, f0.x, fmaf(d1, f1.x, fmaf(d2, f2.x, fmaf(d3, f3.x, a[2*i]))));
                a[2*i+1] = fmaf(d0, f0.y, fmaf(d1, f1.y, fmaf(d2, f2.y, fmaf(d3, f3.y, a[2*i+1]))));
            }
        }
        for (; t < cnt; t += 4) {
            int tg = t + g;
            int sl = tg < 64 ? tg : 0;       // convergent shfl
            int r = __shfl(idx, sl);
            float dd = __shfl(dv, sl);
            if (tg < cnt) {
                f4 v = ((const f4*)(gh + (size_t)r * 256))[li];
                __half2* hv = (__half2*)&v;
#pragma unroll
                for (int i = 0; i < 4; ++i) {
                    float2 f = __half22float2(hv[i]);
                    a[2*i]   = fmaf(dd, f.x, a[2*i]);
                    a[2*i+1] = fmaf(dd, f.y, a[2*i+1]);
                }
            }
        }
    }

#pragma unroll
    for (int j = 0; j < 8; ++j) {
        a[j] += __shfl_xor(a[j], 16);
        a[j] += __shfl_xor(a[j], 32);
    }
    if (g == 0) {
        f4 b0 = bias4[li * 2], b1v = bias4[li * 2 + 1];
        f4 o0, o1;
#pragma unroll
        for (int u = 0; u < 4; ++u) {
            o0[u] = fmaxf(fmaf(di, a[u],     b0[u]),  0.0f);
            o1[u] = fmaxf(fmaf(di, a[4 + u], b1v[u]), 0.0f);
        }
        out4[(size_t)wid * 32 + li * 2]     = o0;
        out4[(size_t)wid * 32 + li * 2 + 1] = o1;
    }
}

// ---------- standalone gemm (layer 2): reads d_out act, writes g16 slots ----------
__global__ __launch_bounds__(256) void gemm_kernel(const float* __restrict__ src,
                                                   const __half* __restrict__ Wt,
                                                   __half* __restrict__ g16, int nrows) {
    __shared__ char smem[65536];
    gemm_body(smem, blockIdx.x, src, Wt, g16, nrows);
}

// ---------- launch ----------
extern "C" void kernel_launch(void* const* d_in, const int* in_sizes, int n_in,
                              void* d_out, int out_size, void* d_ws, size_t ws_size,
                              hipStream_t stream) {
    float*       xbuf = (float*)d_in[0];        // fp32 input; reused as slotted fp16 g-table
    const int*   ei   = (const int*)d_in[1];
    const float* W1   = (const float*)d_in[2];
    const float* b1   = (const float*)d_in[3];
    const float* W2   = (const float*)d_in[4];
    const float* b2   = (const float*)d_in[5];
    float*       out  = (float*)d_out;

    int N = in_sizes[0] / 128;
    int E = in_sizes[1] / 2;
    const int* row = ei;          // sources (x_j)
    const int* col = ei + E;      // targets (aggregate index)

    int nbuck = (N + 255) >> BSHIFT;   // 196 for N=50000

    auto align256 = [](size_t v) { return (v + 255) & ~(size_t)255; };
    char* ws = (char*)d_ws;
    size_t pos = 0;
    int*      off    = (int*)(ws + pos);      pos += align256((size_t)(N + 1) * 4);
    float*    dinv   = (float*)(ws + pos);    pos += align256((size_t)N * 4);
    int*      csr    = (int*)(ws + pos);      pos += align256((size_t)E * 4);
    int*      gcur   = (int*)(ws + pos);      pos += align256(256 * 4);
    uint32_t* binned = (uint32_t*)(ws + pos); pos += align256((size_t)nbuck * BCAP * 4);
    __half*   Wt1    = (__half*)(ws + pos);   pos += align256(128 * 128 * 2);
    __half*   Wt2    = (__half*)(ws + pos);   pos += align256(128 * 128 * 2);
    // total ~10 MB

    __half* g16 = (__half*)xbuf;   // 512-B slots overlaying the fp32 rows

    int binblocks = (E + 1023) / 1024;
    int gblocks   = (N + 63) / 64;
    int ablocks   = (N + 3) / 4;

    // prep: zero gcur + transpose both W's (replaces memset)
    prep_kernel<<<17, 256, 0, stream>>>(W1, W2, Wt1, Wt2, gcur);
    // fused: gemm1 (independent of graph — dinv deferred to agg) + bin
    gemm_bin_kernel<<<gblocks + binblocks, 256, 0, stream>>>(xbuf, Wt1, g16, N, gblocks,
                                                             row, col, gcur, binned,
                                                             E, N, nbuck);
    bucket_kernel<<<nbuck, 1024, 0, stream>>>(binned, gcur, off, dinv, csr, N, nbuck);

    // layer 1: act1 = relu(di*(di*h_self + Σ dv*h) + b1) -> d_out
    agg_f16<<<ablocks, 256, 0, stream>>>(g16, csr, off, dinv, (const f4*)b1, (f4*)out, N);
    // layer 2: g2 = fp16(act1 @ W2) -> slots in xbuf (not in-place now)
    gemm_kernel<<<gblocks, 256, 0, stream>>>(out, Wt2, g16, N);
    agg_f16<<<ablocks, 256, 0, stream>>>(g16, csr, off, dinv, (const f4*)b2, (f4*)out, N);
}

// Round 5
// 191.502 us; speedup vs baseline: 1.2438x; 1.0326x over previous
//
#include <hip/hip_runtime.h>
#include <hip/hip_fp16.h>
#include <stdint.h>

typedef float f4 __attribute__((ext_vector_type(4)));
typedef float f32x4 __attribute__((ext_vector_type(4)));
typedef _Float16 f16x8 __attribute__((ext_vector_type(8)));

#define BSHIFT 8
#define BMASK  255
#define BCAP   8192   // edges per 256-node bucket (mean 4096 -> huge headroom)

// ---------- prep: zero gcur + transpose W1/W2 -> fp16 [c][k] (replaces memset) ----------
__global__ __launch_bounds__(256) void prep_kernel(const float* __restrict__ W1,
                                                   const float* __restrict__ W2,
                                                   __half* __restrict__ Wt1,
                                                   __half* __restrict__ Wt2,
                                                   int* __restrict__ gcur) {
    int t = threadIdx.x, b = blockIdx.x;
    if (b == 0) { gcur[t] = 0; return; }
    int wi = (b - 1) >> 3, bi = (b - 1) & 7;
    const f4* w4 = (const f4*)(wi ? W2 : W1);
    _Float16* dst = (_Float16*)(wi ? Wt2 : Wt1);
#pragma unroll
    for (int it = 0; it < 2; ++it) {
        int chunk = bi * 512 + it * 256 + t;      // f4 index into 128x128 W
        f4 v = w4[chunk];
        int k = chunk >> 5, c0 = (chunk << 2) & 127;
#pragma unroll
        for (int u = 0; u < 4; ++u)
            dst[(size_t)(c0 + u) * 128 + k] = (_Float16)v[u];
    }
}

// ---------- stage B (Wt fp16 [c][k]) into swizzled LDS: byte^=((c&7)<<4) ----------
__device__ __forceinline__ void stage_B(_Float16* Bsw, const __half* __restrict__ Wt) {
    int t = threadIdx.x;
    const f4* wsrc = (const f4*)Wt;
#pragma unroll
    for (int i = 0; i < 8; ++i) {
        int cb = i * 256 + t;
        f4 v = wsrc[cb];
        int lin = cb * 16;
        int c = cb >> 4;
        *(f4*)((char*)Bsw + (lin ^ ((c & 7) << 4))) = v;
    }
}

// ---------- gemm1 body: g16[row] = half(x_f32[row] @ W); A in regs (hi+lo fp16) ----------
// Block = 64 rows x 128 cols, 4 waves. B-only LDS (32 KB) -> 5 blocks/CU.
// In-place over src safe: each wave reads only the rows it writes (loads precede stores).
__device__ __forceinline__ void gemm1_body(char* smem, int blk,
                                           const float* __restrict__ src,
                                           const __half* __restrict__ Wt,
                                           __half* __restrict__ g16, int nrows) {
    _Float16* Bsw = (_Float16*)smem;   // 32 KB
    stage_B(Bsw, Wt);

    int t = threadIdx.x;
    int w = t >> 6, lane = t & 63;
    int li = lane & 15, hg = lane >> 4;
    int r = blk * 64 + w * 16 + li;
    int rc = r < nrows ? r : nrows - 1;
    const float* xr = src + (size_t)rc * 128;

    // A frags direct from global: row r, k = kk*32 + hg*8 .. +7 ; hi + residual
    f16x8 af[4], al[4];
#pragma unroll
    for (int kk = 0; kk < 4; ++kk) {
        f4 v0 = *(const f4*)(xr + kk * 32 + hg * 8);
        f4 v1 = *(const f4*)(xr + kk * 32 + hg * 8 + 4);
#pragma unroll
        for (int u = 0; u < 4; ++u) {
            float a0 = v0[u]; _Float16 h0 = (_Float16)a0;
            af[kk][u] = h0;     al[kk][u]     = (_Float16)(a0 - (float)h0);
            float a1 = v1[u]; _Float16 h1 = (_Float16)a1;
            af[kk][u + 4] = h1; al[kk][u + 4] = (_Float16)(a1 - (float)h1);
        }
    }
    __syncthreads();   // B ready (A loads overlapped with B staging)

    f32x4 acc[8];
#pragma unroll
    for (int nn = 0; nn < 8; ++nn) acc[nn] = (f32x4)0.0f;
#pragma unroll
    for (int nn = 0; nn < 8; ++nn) {
        int c = nn * 16 + li;
        int cbase = c * 256;
        int sw = (c & 7) << 4;
#pragma unroll
        for (int kk = 0; kk < 4; ++kk) {
            f16x8 bf = *(const f16x8*)((const char*)Bsw + ((cbase + kk * 64 + hg * 16) ^ sw));
            acc[nn] = __builtin_amdgcn_mfma_f32_16x16x32_f16(af[kk], bf, acc[nn], 0, 0, 0);
            acc[nn] = __builtin_amdgcn_mfma_f32_16x16x32_f16(al[kk], bf, acc[nn], 0, 0, 0);
        }
    }

    // epilogue: C/D col = lane&15, row = (lane>>4)*4 + reg (m89); 512-B slots
    int gr0 = blk * 64 + w * 16 + (hg << 2);
#pragma unroll
    for (int nn = 0; nn < 8; ++nn) {
        int c = nn * 16 + li;
#pragma unroll
        for (int q = 0; q < 4; ++q) {
            int rr = gr0 + q;
            if (rr < nrows)
                g16[(size_t)rr * 256 + c] = __float2half(acc[nn][q]);
        }
    }
}

// ---------- bin body: 2048 edges/block -> packed (row<<8 | node_in_bucket) ----------
__device__ __forceinline__ void bin_body(char* smem, int bb,
                                         const int* __restrict__ row,
                                         const int* __restrict__ col,
                                         int* __restrict__ gcur,
                                         uint32_t* __restrict__ binned,
                                         int E, int n, int nbuck) {
    int* hist = (int*)smem;
    int* base = (int*)(smem + 1024);
    int t = threadIdx.x;
    hist[t] = 0;
    __syncthreads();
    int e0 = bb * 2048 + t;
    int cc[8]; uint32_t pk[8];
#pragma unroll
    for (int i = 0; i < 8; ++i) {
        int e = e0 + i * 256;
        cc[i] = -1; pk[i] = 0;
        if (e < E) {
            int c = col[e];
            if ((unsigned)c < (unsigned)n) {
                cc[i] = c >> BSHIFT;
                pk[i] = ((uint32_t)row[e] << BSHIFT) | (uint32_t)(c & BMASK);
            }
        }
    }
#pragma unroll
    for (int i = 0; i < 8; ++i)
        if (cc[i] >= 0) atomicAdd(&hist[cc[i]], 1);
    __syncthreads();
    if (t < nbuck) {
        int h = hist[t];
        if (h) base[t] = atomicAdd(&gcur[t], h);
        hist[t] = 0;
    }
    __syncthreads();
#pragma unroll
    for (int i = 0; i < 8; ++i)
        if (cc[i] >= 0) {
            int b = cc[i];
            int p = base[b] + atomicAdd(&hist[b], 1);
            if (p < BCAP) binned[(size_t)b * BCAP + p] = pk[i];
        }
}

// ---------- fused kernel1: gemm1 blocks + bin blocks (disjoint roles, 32 KB LDS) ----------
__global__ __launch_bounds__(256) void gemm_bin_kernel(const float* __restrict__ src,
                                                       const __half* __restrict__ Wt,
                                                       __half* __restrict__ g16,
                                                       int nrows, int gblocks,
                                                       const int* __restrict__ row,
                                                       const int* __restrict__ col,
                                                       int* __restrict__ gcur,
                                                       uint32_t* __restrict__ binned,
                                                       int E, int n, int nbuck) {
    __shared__ char smem[32768];
    if ((int)blockIdx.x < gblocks)
        gemm1_body(smem, blockIdx.x, src, Wt, g16, nrows);
    else
        bin_body(smem, blockIdx.x - gblocks, row, col, gcur, binned, E, n, nbuck);
}

// ---------- gemm2: g16[row] = half(act16[row] @ W); fp16 input -> no residual ----------
__global__ __launch_bounds__(256) void gemm2_kernel(const __half* __restrict__ act16,
                                                    const __half* __restrict__ Wt,
                                                    __half* __restrict__ g16, int nrows) {
    __shared__ char smem[32768];
    _Float16* Bsw = (_Float16*)smem;
    stage_B(Bsw, Wt);

    int t = threadIdx.x;
    int w = t >> 6, lane = t & 63;
    int li = lane & 15, hg = lane >> 4;
    int r = blockIdx.x * 64 + w * 16 + li;
    int rc = r < nrows ? r : nrows - 1;
    const _Float16* xr = (const _Float16*)act16 + (size_t)rc * 128;

    f16x8 af[4];
#pragma unroll
    for (int kk = 0; kk < 4; ++kk)
        af[kk] = *(const f16x8*)(xr + kk * 32 + hg * 8);
    __syncthreads();

    f32x4 acc[8];
#pragma unroll
    for (int nn = 0; nn < 8; ++nn) acc[nn] = (f32x4)0.0f;
#pragma unroll
    for (int nn = 0; nn < 8; ++nn) {
        int c = nn * 16 + li;
        int cbase = c * 256;
        int sw = (c & 7) << 4;
#pragma unroll
        for (int kk = 0; kk < 4; ++kk) {
            f16x8 bf = *(const f16x8*)((const char*)Bsw + ((cbase + kk * 64 + hg * 16) ^ sw));
            acc[nn] = __builtin_amdgcn_mfma_f32_16x16x32_f16(af[kk], bf, acc[nn], 0, 0, 0);
        }
    }

    int gr0 = blockIdx.x * 64 + w * 16 + (hg << 2);
#pragma unroll
    for (int nn = 0; nn < 8; ++nn) {
        int c = nn * 16 + li;
#pragma unroll
        for (int q = 0; q < 4; ++q) {
            int rr = gr0 + q;
            if (rr < nrows)
                g16[(size_t)rr * 256 + c] = __float2half(acc[nn][q]);
        }
    }
}

// ---------- bucket: 1024 threads/block, per 256-node bucket -> off / dinv / csr ----------
__global__ __launch_bounds__(1024) void bucket_kernel(const uint32_t* __restrict__ binned,
                                                      const int* __restrict__ gcur,
                                                      int* __restrict__ off,
                                                      float* __restrict__ dinv,
                                                      int* __restrict__ csr,
                                                      int n, int nbuck) {
    __shared__ int wtot[4];
    __shared__ int sbase[256];
    __shared__ int hist[256];
    __shared__ int cur[256];
    int t = threadIdx.x;
    int lane = t & 63, w = t >> 6;
    int b = blockIdx.x;

    int v = 0, inc = 0;
    if (t < 256) {
        v = (t < nbuck) ? gcur[t] : 0;
        inc = v;
#pragma unroll
        for (int d = 1; d < 64; d <<= 1) { int u = __shfl_up(inc, d); if (lane >= d) inc += u; }
        if (lane == 63) wtot[w] = inc;
    }
    __syncthreads();
    if (t < 256) {
        int wb = 0;
        for (int i = 0; i < w; ++i) wb += wtot[i];
        sbase[t] = wb + inc - v;
    }
    __syncthreads();
    int base_b = sbase[b];
    int c_b    = gcur[b];

    if (t < 256) hist[t] = 0;
    __syncthreads();
    const uint32_t* reg = binned + (size_t)b * BCAP;
    for (int j = t; j < c_b; j += 1024)
        atomicAdd(&hist[reg[j] & BMASK], 1);
    __syncthreads();

    int h = 0, inc2 = 0;
    if (t < 256) {
        h = hist[t];
        inc2 = h;
#pragma unroll
        for (int d = 1; d < 64; d <<= 1) { int u = __shfl_up(inc2, d); if (lane >= d) inc2 += u; }
        if (lane == 63) wtot[w] = inc2;
    }
    __syncthreads();
    if (t < 256) {
        int wb2 = 0;
        for (int i = 0; i < w; ++i) wb2 += wtot[i];
        int lo = wb2 + inc2 - h;
        int node = (b << BSHIFT) + t;
        if (node < n) {
            off[node]  = base_b + lo;
            dinv[node] = rsqrtf((float)(h + 1));   // +1: self-loop
        }
        cur[t] = base_b + lo;
    }
    if (b == nbuck - 1 && t == 0)
        off[n] = sbase[nbuck - 1] + gcur[nbuck - 1];
    __syncthreads();
    for (int j = t; j < c_b; j += 1024) {
        uint32_t pv = reg[j];
        int p = atomicAdd(&cur[pv & BMASK], 1);
        csr[p] = (int)(pv >> BSHIFT);
    }
}

// ---------- aggregation: wave/node, 4x16-lane groups; per-edge dinv gathered ----------
// out[i] = relu( di*( di*h_self + Σ_e dv_e*h_e ) + b );  OUT16: fp16 compact rows
template<int OUT16>
__global__ __launch_bounds__(256) void agg_f16(const __half* __restrict__ gh,   // 512-B slots
                                               const int* __restrict__ csr,
                                               const int* __restrict__ off,
                                               const float* __restrict__ dinv,
                                               const f4* __restrict__ bias4,    // [32]
                                               void* __restrict__ outp,
                                               int n) {
    int wid  = (blockIdx.x * 256 + threadIdx.x) >> 6;
    int lane = threadIdx.x & 63;
    if (wid >= n) return;
    int g  = lane >> 4;
    int li = lane & 15;
    float di = dinv[wid];

    float a[8];
    {
        f4 sv = ((const f4*)(gh + (size_t)wid * 256))[li];   // self row (g==0 only)
        __half2* sh = (__half2*)&sv;
        if (g == 0) {
#pragma unroll
            for (int i = 0; i < 4; ++i) {
                float2 f = __half22float2(sh[i]);
                a[2*i] = di * f.x; a[2*i+1] = di * f.y;
            }
        } else {
#pragma unroll
            for (int j = 0; j < 8; ++j) a[j] = 0.0f;
        }
    }

    int s = off[wid], e = off[wid + 1];
    for (int base = s; base < e; base += 64) {
        int idx = 0; float dv = 0.0f;
        if (base + lane < e) {
            idx = csr[base + lane];          // coalesced
            dv  = dinv[idx];                 // 4B gather
        }
        int cnt = e - base; if (cnt > 64) cnt = 64;
        int t = 0;
        for (; t + 16 <= cnt; t += 16) {     // 16 edges, 4 gathers in flight/lane
            int r0 = __shfl(idx, t + g),      r1 = __shfl(idx, t + 4 + g);
            int r2 = __shfl(idx, t + 8 + g),  r3 = __shfl(idx, t + 12 + g);
            float d0 = __shfl(dv, t + g),     d1 = __shfl(dv, t + 4 + g);
            float d2 = __shfl(dv, t + 8 + g), d3 = __shfl(dv, t + 12 + g);
            f4 v0 = ((const f4*)(gh + (size_t)r0 * 256))[li];
            f4 v1 = ((const f4*)(gh + (size_t)r1 * 256))[li];
            f4 v2 = ((const f4*)(gh + (size_t)r2 * 256))[li];
            f4 v3 = ((const f4*)(gh + (size_t)r3 * 256))[li];
            __half2* h0 = (__half2*)&v0; __half2* h1 = (__half2*)&v1;
            __half2* h2 = (__half2*)&v2; __half2* h3 = (__half2*)&v3;
#pragma unroll
            for (int i = 0; i < 4; ++i) {
                float2 f0 = __half22float2(h0[i]); float2 f1 = __half22float2(h1[i]);
                float2 f2 = __half22float2(h2[i]); float2 f3 = __half22float2(h3[i]);
                a[2*i]   = fmaf(d0, f0.x, fmaf(d1, f1.x, fmaf(d2, f2.x, fmaf(d3, f3.x, a[2*i]))));
                a[2*i+1] = fmaf(d0, f0.y, fmaf(d1, f1.y, fmaf(d2, f2.y, fmaf(d3, f3.y, a[2*i+1]))));
            }
        }
        for (; t < cnt; t += 4) {
            int tg = t + g;
            int sl = tg < 64 ? tg : 0;       // convergent shfl
            int r = __shfl(idx, sl);
            float dd = __shfl(dv, sl);
            if (tg < cnt) {
                f4 v = ((const f4*)(gh + (size_t)r * 256))[li];
                __half2* hv = (__half2*)&v;
#pragma unroll
                for (int i = 0; i < 4; ++i) {
                    float2 f = __half22float2(hv[i]);
                    a[2*i]   = fmaf(dd, f.x, a[2*i]);
                    a[2*i+1] = fmaf(dd, f.y, a[2*i+1]);
                }
            }
        }
    }

#pragma unroll
    for (int j = 0; j < 8; ++j) {
        a[j] += __shfl_xor(a[j], 16);
        a[j] += __shfl_xor(a[j], 32);
    }
    if (g == 0) {
        f4 b0 = bias4[li * 2], b1v = bias4[li * 2 + 1];
        float o[8];
#pragma unroll
        for (int u = 0; u < 4; ++u) {
            o[u]     = fmaxf(fmaf(di, a[u],     b0[u]),  0.0f);
            o[4 + u] = fmaxf(fmaf(di, a[4 + u], b1v[u]), 0.0f);
        }
        if (OUT16) {
            f16x8 hv;
#pragma unroll
            for (int u = 0; u < 8; ++u) hv[u] = (_Float16)o[u];
            *(f16x8*)((_Float16*)outp + (size_t)wid * 128 + li * 8) = hv;
        } else {
            f4 o0, o1;
#pragma unroll
            for (int u = 0; u < 4; ++u) { o0[u] = o[u]; o1[u] = o[4 + u]; }
            f4* out4 = (f4*)outp;
            out4[(size_t)wid * 32 + li * 2]     = o0;
            out4[(size_t)wid * 32 + li * 2 + 1] = o1;
        }
    }
}

// ---------- launch ----------
extern "C" void kernel_launch(void* const* d_in, const int* in_sizes, int n_in,
                              void* d_out, int out_size, void* d_ws, size_t ws_size,
                              hipStream_t stream) {
    float*       xbuf = (float*)d_in[0];        // fp32 input; reused as slotted fp16 g-table
    const int*   ei   = (const int*)d_in[1];
    const float* W1   = (const float*)d_in[2];
    const float* b1   = (const float*)d_in[3];
    const float* W2   = (const float*)d_in[4];
    const float* b2   = (const float*)d_in[5];
    float*       out  = (float*)d_out;

    int N = in_sizes[0] / 128;
    int E = in_sizes[1] / 2;
    const int* row = ei;          // sources (x_j)
    const int* col = ei + E;      // targets (aggregate index)

    int nbuck = (N + 255) >> BSHIFT;   // 196 for N=50000

    auto align256 = [](size_t v) { return (v + 255) & ~(size_t)255; };
    char* ws = (char*)d_ws;
    size_t pos = 0;
    int*      off    = (int*)(ws + pos);      pos += align256((size_t)(N + 1) * 4);
    float*    dinv   = (float*)(ws + pos);    pos += align256((size_t)N * 4);
    int*      csr    = (int*)(ws + pos);      pos += align256((size_t)E * 4);
    int*      gcur   = (int*)(ws + pos);      pos += align256(256 * 4);
    uint32_t* binned = (uint32_t*)(ws + pos); pos += align256((size_t)nbuck * BCAP * 4);
    __half*   Wt1    = (__half*)(ws + pos);   pos += align256(128 * 128 * 2);
    __half*   Wt2    = (__half*)(ws + pos);   pos += align256(128 * 128 * 2);
    // total ~10 MB

    __half* g16   = (__half*)xbuf;   // 512-B slots overlaying the fp32 rows
    __half* act16 = (__half*)out;    // compact fp16 act1 rows (256 B) in d_out scratch

    int binblocks = (E + 2047) / 2048;
    int gblocks   = (N + 63) / 64;
    int ablocks   = (N + 3) / 4;

    // prep: zero gcur + transpose both W's (replaces memset)
    prep_kernel<<<17, 256, 0, stream>>>(W1, W2, Wt1, Wt2, gcur);
    // fused: gemm1 (graph-independent — dinv deferred to agg) + bin
    gemm_bin_kernel<<<gblocks + binblocks, 256, 0, stream>>>(xbuf, Wt1, g16, N, gblocks,
                                                             row, col, gcur, binned,
                                                             E, N, nbuck);
    bucket_kernel<<<nbuck, 1024, 0, stream>>>(binned, gcur, off, dinv, csr, N, nbuck);

    // layer 1: act1 = relu(di*(di*h_self + Σ dv*h) + b1) -> fp16 compact in d_out
    agg_f16<1><<<ablocks, 256, 0, stream>>>(g16, csr, off, dinv, (const f4*)b1, act16, N);
    // layer 2: g2 = fp16(act1 @ W2) -> slots in xbuf (reads d_out, no aliasing)
    gemm2_kernel<<<gblocks, 256, 0, stream>>>(act16, Wt2, g16, N);
    agg_f16<0><<<ablocks, 256, 0, stream>>>(g16, csr, off, dinv, (const f4*)b2, out, N);
}

// Round 6
// 185.612 us; speedup vs baseline: 1.2832x; 1.0317x over previous
//
#include <hip/hip_runtime.h>
#include <hip/hip_fp16.h>
#include <stdint.h>

typedef float f4 __attribute__((ext_vector_type(4)));
typedef float f32x4 __attribute__((ext_vector_type(4)));
typedef _Float16 f16x8 __attribute__((ext_vector_type(8)));

#define BSHIFT 8
#define BMASK  255
#define BCAP   8192   // edges per 256-node bucket (mean 4096 -> huge headroom)

// ---------- prep: zero gcur + transpose W1/W2 -> fp16 [c][k] (replaces memset) ----------
__global__ __launch_bounds__(256) void prep_kernel(const float* __restrict__ W1,
                                                   const float* __restrict__ W2,
                                                   __half* __restrict__ Wt1,
                                                   __half* __restrict__ Wt2,
                                                   int* __restrict__ gcur) {
    int t = threadIdx.x, b = blockIdx.x;
    if (b == 0) { gcur[t] = 0; return; }
    int wi = (b - 1) >> 3, bi = (b - 1) & 7;
    const f4* w4 = (const f4*)(wi ? W2 : W1);
    _Float16* dst = (_Float16*)(wi ? Wt2 : Wt1);
#pragma unroll
    for (int it = 0; it < 2; ++it) {
        int chunk = bi * 512 + it * 256 + t;      // f4 index into 128x128 W
        f4 v = w4[chunk];
        int k = chunk >> 5, c0 = (chunk << 2) & 127;
#pragma unroll
        for (int u = 0; u < 4; ++u)
            dst[(size_t)(c0 + u) * 128 + k] = (_Float16)v[u];
    }
}

// ---------- stage B (Wt fp16 [c][k]) into swizzled LDS: byte^=((c&7)<<4) ----------
__device__ __forceinline__ void stage_B(_Float16* Bsw, const __half* __restrict__ Wt) {
    int t = threadIdx.x;
    const f4* wsrc = (const f4*)Wt;
#pragma unroll
    for (int i = 0; i < 8; ++i) {
        int cb = i * 256 + t;
        f4 v = wsrc[cb];
        int lin = cb * 16;
        int c = cb >> 4;
        *(f4*)((char*)Bsw + (lin ^ ((c & 7) << 4))) = v;
    }
}

// ---------- gemm1 body: g1c[row] = half(x_f32[row] @ W); A in regs (hi+lo fp16) ----------
// Block = 64 rows x 128 cols, 4 waves. B-only LDS (32 KB). Writes COMPACT 256-B rows
// into d_out's upper half (no aliasing with the xbuf source at all).
__device__ __forceinline__ void gemm1_body(char* smem, int blk,
                                           const float* __restrict__ src,
                                           const __half* __restrict__ Wt,
                                           __half* __restrict__ g16, int nrows) {
    _Float16* Bsw = (_Float16*)smem;   // 32 KB
    stage_B(Bsw, Wt);

    int t = threadIdx.x;
    int w = t >> 6, lane = t & 63;
    int li = lane & 15, hg = lane >> 4;
    int r = blk * 64 + w * 16 + li;
    int rc = r < nrows ? r : nrows - 1;
    const float* xr = src + (size_t)rc * 128;

    // A frags direct from global: row r, k = kk*32 + hg*8 .. +7 ; hi + residual
    f16x8 af[4], al[4];
#pragma unroll
    for (int kk = 0; kk < 4; ++kk) {
        f4 v0 = *(const f4*)(xr + kk * 32 + hg * 8);
        f4 v1 = *(const f4*)(xr + kk * 32 + hg * 8 + 4);
#pragma unroll
        for (int u = 0; u < 4; ++u) {
            float a0 = v0[u]; _Float16 h0 = (_Float16)a0;
            af[kk][u] = h0;     al[kk][u]     = (_Float16)(a0 - (float)h0);
            float a1 = v1[u]; _Float16 h1 = (_Float16)a1;
            af[kk][u + 4] = h1; al[kk][u + 4] = (_Float16)(a1 - (float)h1);
        }
    }
    __syncthreads();   // B ready (A loads overlapped with B staging)

    f32x4 acc[8];
#pragma unroll
    for (int nn = 0; nn < 8; ++nn) acc[nn] = (f32x4)0.0f;
#pragma unroll
    for (int nn = 0; nn < 8; ++nn) {
        int c = nn * 16 + li;
        int cbase = c * 256;
        int sw = (c & 7) << 4;
#pragma unroll
        for (int kk = 0; kk < 4; ++kk) {
            f16x8 bf = *(const f16x8*)((const char*)Bsw + ((cbase + kk * 64 + hg * 16) ^ sw));
            acc[nn] = __builtin_amdgcn_mfma_f32_16x16x32_f16(af[kk], bf, acc[nn], 0, 0, 0);
            acc[nn] = __builtin_amdgcn_mfma_f32_16x16x32_f16(al[kk], bf, acc[nn], 0, 0, 0);
        }
    }

    // epilogue: C/D col = lane&15, row = (lane>>4)*4 + reg (m89); COMPACT 256-B rows
    int gr0 = blk * 64 + w * 16 + (hg << 2);
#pragma unroll
    for (int nn = 0; nn < 8; ++nn) {
        int c = nn * 16 + li;
#pragma unroll
        for (int q = 0; q < 4; ++q) {
            int rr = gr0 + q;
            if (rr < nrows)
                g16[(size_t)rr * 128 + c] = __float2half(acc[nn][q]);
        }
    }
}

// ---------- bin body: 2048 edges/block -> packed (row<<8 | node_in_bucket) ----------
__device__ __forceinline__ void bin_body(char* smem, int bb,
                                         const int* __restrict__ row,
                                         const int* __restrict__ col,
                                         int* __restrict__ gcur,
                                         uint32_t* __restrict__ binned,
                                         int E, int n, int nbuck) {
    int* hist = (int*)smem;
    int* base = (int*)(smem + 1024);
    int t = threadIdx.x;
    hist[t] = 0;
    __syncthreads();
    int e0 = bb * 2048 + t;
    int cc[8]; uint32_t pk[8];
#pragma unroll
    for (int i = 0; i < 8; ++i) {
        int e = e0 + i * 256;
        cc[i] = -1; pk[i] = 0;
        if (e < E) {
            int c = col[e];
            if ((unsigned)c < (unsigned)n) {
                cc[i] = c >> BSHIFT;
                pk[i] = ((uint32_t)row[e] << BSHIFT) | (uint32_t)(c & BMASK);
            }
        }
    }
#pragma unroll
    for (int i = 0; i < 8; ++i)
        if (cc[i] >= 0) atomicAdd(&hist[cc[i]], 1);
    __syncthreads();
    if (t < nbuck) {
        int h = hist[t];
        if (h) base[t] = atomicAdd(&gcur[t], h);
        hist[t] = 0;
    }
    __syncthreads();
#pragma unroll
    for (int i = 0; i < 8; ++i)
        if (cc[i] >= 0) {
            int b = cc[i];
            int p = base[b] + atomicAdd(&hist[b], 1);
            if (p < BCAP) binned[(size_t)b * BCAP + p] = pk[i];
        }
}

// ---------- fused kernel1: gemm1 blocks + bin blocks (disjoint roles, 32 KB LDS) ----------
__global__ __launch_bounds__(256) void gemm_bin_kernel(const float* __restrict__ src,
                                                       const __half* __restrict__ Wt,
                                                       __half* __restrict__ g16,
                                                       int nrows, int gblocks,
                                                       const int* __restrict__ row,
                                                       const int* __restrict__ col,
                                                       int* __restrict__ gcur,
                                                       uint32_t* __restrict__ binned,
                                                       int E, int n, int nbuck) {
    __shared__ char smem[32768];
    if ((int)blockIdx.x < gblocks)
        gemm1_body(smem, blockIdx.x, src, Wt, g16, nrows);
    else
        bin_body(smem, blockIdx.x - gblocks, row, col, gcur, binned, E, n, nbuck);
}

// ---------- gemm2: g2c[row] = half(dinv[row] * (act16[row] @ W)); compact rows ----------
// Pre-scaling by dinv here (graph known by now) removes the per-edge dinv gather in agg2.
__global__ __launch_bounds__(256) void gemm2_kernel(const __half* __restrict__ act16,
                                                    const __half* __restrict__ Wt,
                                                    const float* __restrict__ dinv,
                                                    __half* __restrict__ g16, int nrows) {
    __shared__ char smem[32768];
    _Float16* Bsw = (_Float16*)smem;
    stage_B(Bsw, Wt);

    int t = threadIdx.x;
    int w = t >> 6, lane = t & 63;
    int li = lane & 15, hg = lane >> 4;
    int r = blockIdx.x * 64 + w * 16 + li;
    int rc = r < nrows ? r : nrows - 1;
    const _Float16* xr = (const _Float16*)act16 + (size_t)rc * 128;

    f16x8 af[4];
#pragma unroll
    for (int kk = 0; kk < 4; ++kk)
        af[kk] = *(const f16x8*)(xr + kk * 32 + hg * 8);
    __syncthreads();

    f32x4 acc[8];
#pragma unroll
    for (int nn = 0; nn < 8; ++nn) acc[nn] = (f32x4)0.0f;
#pragma unroll
    for (int nn = 0; nn < 8; ++nn) {
        int c = nn * 16 + li;
        int cbase = c * 256;
        int sw = (c & 7) << 4;
#pragma unroll
        for (int kk = 0; kk < 4; ++kk) {
            f16x8 bf = *(const f16x8*)((const char*)Bsw + ((cbase + kk * 64 + hg * 16) ^ sw));
            acc[nn] = __builtin_amdgcn_mfma_f32_16x16x32_f16(af[kk], bf, acc[nn], 0, 0, 0);
        }
    }

    int gr0 = blockIdx.x * 64 + w * 16 + (hg << 2);
    float dv[4];
#pragma unroll
    for (int q = 0; q < 4; ++q) {
        int rr = gr0 + q;
        dv[q] = dinv[rr < nrows ? rr : 0];
    }
#pragma unroll
    for (int nn = 0; nn < 8; ++nn) {
        int c = nn * 16 + li;
#pragma unroll
        for (int q = 0; q < 4; ++q) {
            int rr = gr0 + q;
            if (rr < nrows)
                g16[(size_t)rr * 128 + c] = __float2half(acc[nn][q] * dv[q]);
        }
    }
}

// ---------- bucket: 1024 threads/block, per 256-node bucket -> off / dinv / csr ----------
__global__ __launch_bounds__(1024) void bucket_kernel(const uint32_t* __restrict__ binned,
                                                      const int* __restrict__ gcur,
                                                      int* __restrict__ off,
                                                      float* __restrict__ dinv,
                                                      int* __restrict__ csr,
                                                      int n, int nbuck) {
    __shared__ int wtot[4];
    __shared__ int sbase[256];
    __shared__ int hist[256];
    __shared__ int cur[256];
    int t = threadIdx.x;
    int lane = t & 63, w = t >> 6;
    int b = blockIdx.x;

    int v = 0, inc = 0;
    if (t < 256) {
        v = (t < nbuck) ? gcur[t] : 0;
        inc = v;
#pragma unroll
        for (int d = 1; d < 64; d <<= 1) { int u = __shfl_up(inc, d); if (lane >= d) inc += u; }
        if (lane == 63) wtot[w] = inc;
    }
    __syncthreads();
    if (t < 256) {
        int wb = 0;
        for (int i = 0; i < w; ++i) wb += wtot[i];
        sbase[t] = wb + inc - v;
    }
    __syncthreads();
    int base_b = sbase[b];
    int c_b    = gcur[b];

    if (t < 256) hist[t] = 0;
    __syncthreads();
    const uint32_t* reg = binned + (size_t)b * BCAP;
    for (int j = t; j < c_b; j += 1024)
        atomicAdd(&hist[reg[j] & BMASK], 1);
    __syncthreads();

    int h = 0, inc2 = 0;
    if (t < 256) {
        h = hist[t];
        inc2 = h;
#pragma unroll
        for (int d = 1; d < 64; d <<= 1) { int u = __shfl_up(inc2, d); if (lane >= d) inc2 += u; }
        if (lane == 63) wtot[w] = inc2;
    }
    __syncthreads();
    if (t < 256) {
        int wb2 = 0;
        for (int i = 0; i < w; ++i) wb2 += wtot[i];
        int lo = wb2 + inc2 - h;
        int node = (b << BSHIFT) + t;
        if (node < n) {
            off[node]  = base_b + lo;
            dinv[node] = rsqrtf((float)(h + 1));   // +1: self-loop
        }
        cur[t] = base_b + lo;
    }
    if (b == nbuck - 1 && t == 0)
        off[n] = sbase[nbuck - 1] + gcur[nbuck - 1];
    __syncthreads();
    for (int j = t; j < c_b; j += 1024) {
        uint32_t pv = reg[j];
        int p = atomicAdd(&cur[pv & BMASK], 1);
        csr[p] = (int)(pv >> BSHIFT);
    }
}

// ---------- aggregation: wave/node, 4x16-lane groups; COMPACT 256-B g-rows ----------
// PRE=0: out = relu(di*(di*h_self + Σ dv_e*h_e) + b)   (dv gathered per edge)
// PRE=1: rows pre-scaled by own dinv -> out = relu(di*(g'_self + Σ g'_e) + b)
template<int OUT16, int PRE>
__global__ __launch_bounds__(256) void agg_f16(const __half* __restrict__ gh,
                                               const int* __restrict__ csr,
                                               const int* __restrict__ off,
                                               const float* __restrict__ dinv,
                                               const f4* __restrict__ bias4,    // [32]
                                               void* __restrict__ outp,
                                               int n) {
    int wid  = (blockIdx.x * 256 + threadIdx.x) >> 6;
    int lane = threadIdx.x & 63;
    if (wid >= n) return;
    int g  = lane >> 4;
    int li = lane & 15;
    float di = dinv[wid];

    float a[8];
    {
        f4 sv = ((const f4*)(gh + (size_t)wid * 128))[li];   // self row (g==0 only)
        __half2* sh = (__half2*)&sv;
        if (g == 0) {
            float sc = PRE ? 1.0f : di;
#pragma unroll
            for (int i = 0; i < 4; ++i) {
                float2 f = __half22float2(sh[i]);
                a[2*i] = sc * f.x; a[2*i+1] = sc * f.y;
            }
        } else {
#pragma unroll
            for (int j = 0; j < 8; ++j) a[j] = 0.0f;
        }
    }

    int s = off[wid], e = off[wid + 1];
    for (int base = s; base < e; base += 64) {
        int idx = 0; float dv = 0.0f;
        if (base + lane < e) {
            idx = csr[base + lane];          // coalesced
            if (!PRE) dv = dinv[idx];        // 4B gather (layer-1 only)
        }
        int cnt = e - base; if (cnt > 64) cnt = 64;
        int t = 0;
        for (; t + 16 <= cnt; t += 16) {     // 16 edges, 4 gathers in flight/lane
            int r0 = __shfl(idx, t + g),      r1 = __shfl(idx, t + 4 + g);
            int r2 = __shfl(idx, t + 8 + g),  r3 = __shfl(idx, t + 12 + g);
            f4 v0 = ((const f4*)(gh + (size_t)r0 * 128))[li];
            f4 v1 = ((const f4*)(gh + (size_t)r1 * 128))[li];
            f4 v2 = ((const f4*)(gh + (size_t)r2 * 128))[li];
            f4 v3 = ((const f4*)(gh + (size_t)r3 * 128))[li];
            __half2* h0 = (__half2*)&v0; __half2* h1 = (__half2*)&v1;
            __half2* h2 = (__half2*)&v2; __half2* h3 = (__half2*)&v3;
            if (PRE) {
#pragma unroll
                for (int i = 0; i < 4; ++i) {
                    float2 f0 = __half22float2(h0[i]); float2 f1 = __half22float2(h1[i]);
                    float2 f2 = __half22float2(h2[i]); float2 f3 = __half22float2(h3[i]);
                    a[2*i]   += (f0.x + f1.x) + (f2.x + f3.x);
                    a[2*i+1] += (f0.y + f1.y) + (f2.y + f3.y);
                }
            } else {
                float d0 = __shfl(dv, t + g),     d1 = __shfl(dv, t + 4 + g);
                float d2 = __shfl(dv, t + 8 + g), d3 = __shfl(dv, t + 12 + g);
#pragma unroll
                for (int i = 0; i < 4; ++i) {
                    float2 f0 = __half22float2(h0[i]); float2 f1 = __half22float2(h1[i]);
                    float2 f2 = __half22float2(h2[i]); float2 f3 = __half22float2(h3[i]);
                    a[2*i]   = fmaf(d0, f0.x, fmaf(d1, f1.x, fmaf(d2, f2.x, fmaf(d3, f3.x, a[2*i]))));
                    a[2*i+1] = fmaf(d0, f0.y, fmaf(d1, f1.y, fmaf(d2, f2.y, fmaf(d3, f3.y, a[2*i+1]))));
                }
            }
        }
        for (; t < cnt; t += 4) {
            int tg = t + g;
            int sl = tg < 64 ? tg : 0;       // convergent shfl
            int r = __shfl(idx, sl);
            float dd = PRE ? 1.0f : __shfl(dv, sl);
            if (tg < cnt) {
                f4 v = ((const f4*)(gh + (size_t)r * 128))[li];
                __half2* hv = (__half2*)&v;
#pragma unroll
                for (int i = 0; i < 4; ++i) {
                    float2 f = __half22float2(hv[i]);
                    if (PRE) { a[2*i] += f.x; a[2*i+1] += f.y; }
                    else {
                        a[2*i]   = fmaf(dd, f.x, a[2*i]);
                        a[2*i+1] = fmaf(dd, f.y, a[2*i+1]);
                    }
                }
            }
        }
    }

#pragma unroll
    for (int j = 0; j < 8; ++j) {
        a[j] += __shfl_xor(a[j], 16);
        a[j] += __shfl_xor(a[j], 32);
    }
    if (g == 0) {
        f4 b0 = bias4[li * 2], b1v = bias4[li * 2 + 1];
        float o[8];
#pragma unroll
        for (int u = 0; u < 4; ++u) {
            o[u]     = fmaxf(fmaf(di, a[u],     b0[u]),  0.0f);
            o[4 + u] = fmaxf(fmaf(di, a[4 + u], b1v[u]), 0.0f);
        }
        if (OUT16) {
            f16x8 hv;
#pragma unroll
            for (int u = 0; u < 8; ++u) hv[u] = (_Float16)o[u];
            *(f16x8*)((_Float16*)outp + (size_t)wid * 128 + li * 8) = hv;
        } else {
            f4 o0, o1;
#pragma unroll
            for (int u = 0; u < 4; ++u) { o0[u] = o[u]; o1[u] = o[4 + u]; }
            f4* out4 = (f4*)outp;
            out4[(size_t)wid * 32 + li * 2]     = o0;
            out4[(size_t)wid * 32 + li * 2 + 1] = o1;
        }
    }
}

// ---------- launch ----------
extern "C" void kernel_launch(void* const* d_in, const int* in_sizes, int n_in,
                              void* d_out, int out_size, void* d_ws, size_t ws_size,
                              hipStream_t stream) {
    float*       xbuf = (float*)d_in[0];        // fp32 input; later reused for compact g2
    const int*   ei   = (const int*)d_in[1];
    const float* W1   = (const float*)d_in[2];
    const float* b1   = (const float*)d_in[3];
    const float* W2   = (const float*)d_in[4];
    const float* b2   = (const float*)d_in[5];
    float*       out  = (float*)d_out;

    int N = in_sizes[0] / 128;
    int E = in_sizes[1] / 2;
    const int* row = ei;          // sources (x_j)
    const int* col = ei + E;      // targets (aggregate index)

    int nbuck = (N + 255) >> BSHIFT;   // 196 for N=50000

    auto align256 = [](size_t v) { return (v + 255) & ~(size_t)255; };
    char* ws = (char*)d_ws;
    size_t pos = 0;
    int*      off    = (int*)(ws + pos);      pos += align256((size_t)(N + 1) * 4);
    float*    dinv   = (float*)(ws + pos);    pos += align256((size_t)N * 4);
    int*      csr    = (int*)(ws + pos);      pos += align256((size_t)E * 4);
    int*      gcur   = (int*)(ws + pos);      pos += align256(256 * 4);
    uint32_t* binned = (uint32_t*)(ws + pos); pos += align256((size_t)nbuck * BCAP * 4);
    __half*   Wt1    = (__half*)(ws + pos);   pos += align256(128 * 128 * 2);
    __half*   Wt2    = (__half*)(ws + pos);   pos += align256(128 * 128 * 2);
    // total ~10 MB

    // buffer routing (all compact 256-B fp16 rows, nothing in-place):
    //   g1c   : d_out upper half (written by gemm1, read by agg1)
    //   act16 : d_out lower half (written by agg1, read by gemm2)
    //   g2c   : xbuf             (written by gemm2, read by agg2)
    //   final : d_out full       (written by agg2)
    __half* act16 = (__half*)out;
    __half* g1c   = (__half*)((char*)out + (size_t)N * 256);
    __half* g2c   = (__half*)xbuf;

    int binblocks = (E + 2047) / 2048;
    int gblocks   = (N + 63) / 64;
    int ablocks   = (N + 3) / 4;

    // prep: zero gcur + transpose both W's (replaces memset)
    prep_kernel<<<17, 256, 0, stream>>>(W1, W2, Wt1, Wt2, gcur);
    // fused: gemm1 (graph-independent — dinv deferred to agg) + bin
    gemm_bin_kernel<<<gblocks + binblocks, 256, 0, stream>>>(xbuf, Wt1, g1c, N, gblocks,
                                                             row, col, gcur, binned,
                                                             E, N, nbuck);
    bucket_kernel<<<nbuck, 1024, 0, stream>>>(binned, gcur, off, dinv, csr, N, nbuck);

    // layer 1: act1 = relu(di*(di*h_self + Σ dv*h) + b1) -> fp16 compact (d_out lower)
    agg_f16<1, 0><<<ablocks, 256, 0, stream>>>(g1c, csr, off, dinv, (const f4*)b1, act16, N);
    // layer 2: g2' = fp16(dinv * (act1 @ W2)) -> xbuf (pre-scaled rows)
    gemm2_kernel<<<gblocks, 256, 0, stream>>>(act16, Wt2, dinv, g2c, N);
    // agg2: out = relu(di*(g'_self + Σ g'_e) + b2) — no per-edge dinv gather
    agg_f16<0, 1><<<ablocks, 256, 0, stream>>>(g2c, csr, off, dinv, (const f4*)b2, out, N);
}

// Round 7
// 181.573 us; speedup vs baseline: 1.3118x; 1.0222x over previous
//
#include <hip/hip_runtime.h>
#include <hip/hip_fp16.h>
#include <stdint.h>

typedef float f4 __attribute__((ext_vector_type(4)));
typedef float f32x4 __attribute__((ext_vector_type(4)));
typedef _Float16 f16x8 __attribute__((ext_vector_type(8)));

#define BSHIFT 8
#define BMASK  255
#define BCAP   8192   // edges per 256-node bucket (mean 4096 -> huge headroom)

// ---------- prep: zero gcur + transpose W1/W2 -> fp16 [c][k] (replaces memset) ----------
__global__ __launch_bounds__(256) void prep_kernel(const float* __restrict__ W1,
                                                   const float* __restrict__ W2,
                                                   __half* __restrict__ Wt1,
                                                   __half* __restrict__ Wt2,
                                                   int* __restrict__ gcur) {
    int t = threadIdx.x, b = blockIdx.x;
    if (b == 0) { gcur[t] = 0; return; }
    int wi = (b - 1) >> 3, bi = (b - 1) & 7;
    const f4* w4 = (const f4*)(wi ? W2 : W1);
    _Float16* dst = (_Float16*)(wi ? Wt2 : Wt1);
#pragma unroll
    for (int it = 0; it < 2; ++it) {
        int chunk = bi * 512 + it * 256 + t;      // f4 index into 128x128 W
        f4 v = w4[chunk];
        int k = chunk >> 5, c0 = (chunk << 2) & 127;
#pragma unroll
        for (int u = 0; u < 4; ++u)
            dst[(size_t)(c0 + u) * 128 + k] = (_Float16)v[u];
    }
}

// ---------- stage B (Wt fp16 [c][k]) into swizzled LDS: byte^=((c&7)<<4) ----------
__device__ __forceinline__ void stage_B(_Float16* Bsw, const __half* __restrict__ Wt) {
    int t = threadIdx.x;
    const f4* wsrc = (const f4*)Wt;
#pragma unroll
    for (int i = 0; i < 8; ++i) {
        int cb = i * 256 + t;
        f4 v = wsrc[cb];
        int lin = cb * 16;
        int c = cb >> 4;
        *(f4*)((char*)Bsw + (lin ^ ((c & 7) << 4))) = v;
    }
}

// ---------- gemm1 body: g1c[row] = half(x_f32[row] @ W); A in regs (hi+lo fp16) ----------
// Block = 64 rows x 128 cols, 4 waves. B-only LDS (32 KB). Writes COMPACT 256-B rows
// into d_out's upper half (no aliasing with the xbuf source at all).
__device__ __forceinline__ void gemm1_body(char* smem, int blk,
                                           const float* __restrict__ src,
                                           const __half* __restrict__ Wt,
                                           __half* __restrict__ g16, int nrows) {
    _Float16* Bsw = (_Float16*)smem;   // 32 KB
    stage_B(Bsw, Wt);

    int t = threadIdx.x;
    int w = t >> 6, lane = t & 63;
    int li = lane & 15, hg = lane >> 4;
    int r = blk * 64 + w * 16 + li;
    int rc = r < nrows ? r : nrows - 1;
    const float* xr = src + (size_t)rc * 128;

    // A frags direct from global: row r, k = kk*32 + hg*8 .. +7 ; hi + residual
    f16x8 af[4], al[4];
#pragma unroll
    for (int kk = 0; kk < 4; ++kk) {
        f4 v0 = *(const f4*)(xr + kk * 32 + hg * 8);
        f4 v1 = *(const f4*)(xr + kk * 32 + hg * 8 + 4);
#pragma unroll
        for (int u = 0; u < 4; ++u) {
            float a0 = v0[u]; _Float16 h0 = (_Float16)a0;
            af[kk][u] = h0;     al[kk][u]     = (_Float16)(a0 - (float)h0);
            float a1 = v1[u]; _Float16 h1 = (_Float16)a1;
            af[kk][u + 4] = h1; al[kk][u + 4] = (_Float16)(a1 - (float)h1);
        }
    }
    __syncthreads();   // B ready (A loads overlapped with B staging)

    f32x4 acc[8];
#pragma unroll
    for (int nn = 0; nn < 8; ++nn) acc[nn] = (f32x4)0.0f;
#pragma unroll
    for (int nn = 0; nn < 8; ++nn) {
        int c = nn * 16 + li;
        int cbase = c * 256;
        int sw = (c & 7) << 4;
#pragma unroll
        for (int kk = 0; kk < 4; ++kk) {
            f16x8 bf = *(const f16x8*)((const char*)Bsw + ((cbase + kk * 64 + hg * 16) ^ sw));
            acc[nn] = __builtin_amdgcn_mfma_f32_16x16x32_f16(af[kk], bf, acc[nn], 0, 0, 0);
            acc[nn] = __builtin_amdgcn_mfma_f32_16x16x32_f16(al[kk], bf, acc[nn], 0, 0, 0);
        }
    }

    // epilogue: C/D col = lane&15, row = (lane>>4)*4 + reg (m89); COMPACT 256-B rows
    int gr0 = blk * 64 + w * 16 + (hg << 2);
#pragma unroll
    for (int nn = 0; nn < 8; ++nn) {
        int c = nn * 16 + li;
#pragma unroll
        for (int q = 0; q < 4; ++q) {
            int rr = gr0 + q;
            if (rr < nrows)
                g16[(size_t)rr * 128 + c] = __float2half(acc[nn][q]);
        }
    }
}

// ---------- bin body: 2048 edges/block -> packed (row<<8 | node_in_bucket) ----------
__device__ __forceinline__ void bin_body(char* smem, int bb,
                                         const int* __restrict__ row,
                                         const int* __restrict__ col,
                                         int* __restrict__ gcur,
                                         uint32_t* __restrict__ binned,
                                         int E, int n, int nbuck) {
    int* hist = (int*)smem;
    int* base = (int*)(smem + 1024);
    int t = threadIdx.x;
    hist[t] = 0;
    __syncthreads();
    int e0 = bb * 2048 + t;
    int cc[8]; uint32_t pk[8];
#pragma unroll
    for (int i = 0; i < 8; ++i) {
        int e = e0 + i * 256;
        cc[i] = -1; pk[i] = 0;
        if (e < E) {
            int c = col[e];
            if ((unsigned)c < (unsigned)n) {
                cc[i] = c >> BSHIFT;
                pk[i] = ((uint32_t)row[e] << BSHIFT) | (uint32_t)(c & BMASK);
            }
        }
    }
#pragma unroll
    for (int i = 0; i < 8; ++i)
        if (cc[i] >= 0) atomicAdd(&hist[cc[i]], 1);
    __syncthreads();
    if (t < nbuck) {
        int h = hist[t];
        if (h) base[t] = atomicAdd(&gcur[t], h);
        hist[t] = 0;
    }
    __syncthreads();
#pragma unroll
    for (int i = 0; i < 8; ++i)
        if (cc[i] >= 0) {
            int b = cc[i];
            int p = base[b] + atomicAdd(&hist[b], 1);
            if (p < BCAP) binned[(size_t)b * BCAP + p] = pk[i];
        }
}

// ---------- fused kernel1: gemm1 blocks + bin blocks (disjoint roles, 32 KB LDS) ----------
__global__ __launch_bounds__(256) void gemm_bin_kernel(const float* __restrict__ src,
                                                       const __half* __restrict__ Wt,
                                                       __half* __restrict__ g16,
                                                       int nrows, int gblocks,
                                                       const int* __restrict__ row,
                                                       const int* __restrict__ col,
                                                       int* __restrict__ gcur,
                                                       uint32_t* __restrict__ binned,
                                                       int E, int n, int nbuck) {
    __shared__ char smem[32768];
    if ((int)blockIdx.x < gblocks)
        gemm1_body(smem, blockIdx.x, src, Wt, g16, nrows);
    else
        bin_body(smem, blockIdx.x - gblocks, row, col, gcur, binned, E, n, nbuck);
}

// ---------- gemm2: g2c[row] = half(dinv[row] * (act16[row] @ W)); compact rows ----------
// Pre-scaling by dinv here (graph known by now) removes the per-edge dinv gather in agg2.
__global__ __launch_bounds__(256) void gemm2_kernel(const __half* __restrict__ act16,
                                                    const __half* __restrict__ Wt,
                                                    const float* __restrict__ dinv,
                                                    __half* __restrict__ g16, int nrows) {
    __shared__ char smem[32768];
    _Float16* Bsw = (_Float16*)smem;
    stage_B(Bsw, Wt);

    int t = threadIdx.x;
    int w = t >> 6, lane = t & 63;
    int li = lane & 15, hg = lane >> 4;
    int r = blockIdx.x * 64 + w * 16 + li;
    int rc = r < nrows ? r : nrows - 1;
    const _Float16* xr = (const _Float16*)act16 + (size_t)rc * 128;

    f16x8 af[4];
#pragma unroll
    for (int kk = 0; kk < 4; ++kk)
        af[kk] = *(const f16x8*)(xr + kk * 32 + hg * 8);
    __syncthreads();

    f32x4 acc[8];
#pragma unroll
    for (int nn = 0; nn < 8; ++nn) acc[nn] = (f32x4)0.0f;
#pragma unroll
    for (int nn = 0; nn < 8; ++nn) {
        int c = nn * 16 + li;
        int cbase = c * 256;
        int sw = (c & 7) << 4;
#pragma unroll
        for (int kk = 0; kk < 4; ++kk) {
            f16x8 bf = *(const f16x8*)((const char*)Bsw + ((cbase + kk * 64 + hg * 16) ^ sw));
            acc[nn] = __builtin_amdgcn_mfma_f32_16x16x32_f16(af[kk], bf, acc[nn], 0, 0, 0);
        }
    }

    int gr0 = blockIdx.x * 64 + w * 16 + (hg << 2);
    float dv[4];
#pragma unroll
    for (int q = 0; q < 4; ++q) {
        int rr = gr0 + q;
        dv[q] = dinv[rr < nrows ? rr : 0];
    }
#pragma unroll
    for (int nn = 0; nn < 8; ++nn) {
        int c = nn * 16 + li;
#pragma unroll
        for (int q = 0; q < 4; ++q) {
            int rr = gr0 + q;
            if (rr < nrows)
                g16[(size_t)rr * 128 + c] = __float2half(acc[nn][q] * dv[q]);
        }
    }
}

// ---------- bucket: 1024 threads/block, per 256-node bucket -> off / dinv / csr ----------
__global__ __launch_bounds__(1024) void bucket_kernel(const uint32_t* __restrict__ binned,
                                                      const int* __restrict__ gcur,
                                                      int* __restrict__ off,
                                                      float* __restrict__ dinv,
                                                      int* __restrict__ csr,
                                                      int n, int nbuck) {
    __shared__ int wtot[4];
    __shared__ int sbase[256];
    __shared__ int hist[256];
    __shared__ int cur[256];
    int t = threadIdx.x;
    int lane = t & 63, w = t >> 6;
    int b = blockIdx.x;

    int v = 0, inc = 0;
    if (t < 256) {
        v = (t < nbuck) ? gcur[t] : 0;
        inc = v;
#pragma unroll
        for (int d = 1; d < 64; d <<= 1) { int u = __shfl_up(inc, d); if (lane >= d) inc += u; }
        if (lane == 63) wtot[w] = inc;
    }
    __syncthreads();
    if (t < 256) {
        int wb = 0;
        for (int i = 0; i < w; ++i) wb += wtot[i];
        sbase[t] = wb + inc - v;
    }
    __syncthreads();
    int base_b = sbase[b];
    int c_b    = gcur[b];

    if (t < 256) hist[t] = 0;
    __syncthreads();
    const uint32_t* reg = binned + (size_t)b * BCAP;
    for (int j = t; j < c_b; j += 1024)
        atomicAdd(&hist[reg[j] & BMASK], 1);
    __syncthreads();

    int h = 0, inc2 = 0;
    if (t < 256) {
        h = hist[t];
        inc2 = h;
#pragma unroll
        for (int d = 1; d < 64; d <<= 1) { int u = __shfl_up(inc2, d); if (lane >= d) inc2 += u; }
        if (lane == 63) wtot[w] = inc2;
    }
    __syncthreads();
    if (t < 256) {
        int wb2 = 0;
        for (int i = 0; i < w; ++i) wb2 += wtot[i];
        int lo = wb2 + inc2 - h;
        int node = (b << BSHIFT) + t;
        if (node < n) {
            off[node]  = base_b + lo;
            dinv[node] = rsqrtf((float)(h + 1));   // +1: self-loop
        }
        cur[t] = base_b + lo;
    }
    if (b == nbuck - 1 && t == 0)
        off[n] = sbase[nbuck - 1] + gcur[nbuck - 1];
    __syncthreads();
    for (int j = t; j < c_b; j += 1024) {
        uint32_t pv = reg[j];
        int p = atomicAdd(&cur[pv & BMASK], 1);
        csr[p] = (int)(pv >> BSHIFT);
    }
}

// ---------- aggregation: wave/node, 4x16-lane groups; COMPACT 256-B g-rows ----------
// Unified weight-padded loop: every 16-edge sub-chunk runs the 4-gather MLP body;
// lanes past the adjacency end carry weight 0 (and idx 0 -> cache-hot row 0), so
// padded terms add exactly 0. No serial tail.
// PRE=0: weight = dinv[idx]; out = relu(di*(di*h_self + Σ w_e*h_e) + b)
// PRE=1: weight = 1;          out = relu(di*(g'_self + Σ g'_e) + b)
template<int OUT16, int PRE>
__global__ __launch_bounds__(256) void agg_f16(const __half* __restrict__ gh,
                                               const int* __restrict__ csr,
                                               const int* __restrict__ off,
                                               const float* __restrict__ dinv,
                                               const f4* __restrict__ bias4,    // [32]
                                               void* __restrict__ outp,
                                               int n) {
    int wid  = (blockIdx.x * 256 + threadIdx.x) >> 6;
    int lane = threadIdx.x & 63;
    if (wid >= n) return;
    int g  = lane >> 4;
    int li = lane & 15;
    float di = dinv[wid];

    float a[8];
    {
        f4 sv = ((const f4*)(gh + (size_t)wid * 128))[li];   // self row (g==0 only)
        __half2* sh = (__half2*)&sv;
        if (g == 0) {
            float sc = PRE ? 1.0f : di;
#pragma unroll
            for (int i = 0; i < 4; ++i) {
                float2 f = __half22float2(sh[i]);
                a[2*i] = sc * f.x; a[2*i+1] = sc * f.y;
            }
        } else {
#pragma unroll
            for (int j = 0; j < 8; ++j) a[j] = 0.0f;
        }
    }

    int s = off[wid], e = off[wid + 1];
    for (int base = s; base < e; base += 64) {
        int idx = 0; float wv = 0.0f;
        if (base + lane < e) {
            idx = csr[base + lane];               // coalesced
            wv  = PRE ? 1.0f : dinv[idx];         // edge weight (0 for pad lanes)
        }
        int cnt = e - base; if (cnt > 64) cnt = 64;
        for (int t = 0; t < cnt; t += 16) {       // all chunks: 4 gathers in flight/lane
            int r0 = __shfl(idx, t + g),      r1 = __shfl(idx, t + 4 + g);
            int r2 = __shfl(idx, t + 8 + g),  r3 = __shfl(idx, t + 12 + g);
            float d0 = __shfl(wv, t + g),     d1 = __shfl(wv, t + 4 + g);
            float d2 = __shfl(wv, t + 8 + g), d3 = __shfl(wv, t + 12 + g);
            f4 v0 = ((const f4*)(gh + (size_t)r0 * 128))[li];
            f4 v1 = ((const f4*)(gh + (size_t)r1 * 128))[li];
            f4 v2 = ((const f4*)(gh + (size_t)r2 * 128))[li];
            f4 v3 = ((const f4*)(gh + (size_t)r3 * 128))[li];
            __half2* h0 = (__half2*)&v0; __half2* h1 = (__half2*)&v1;
            __half2* h2 = (__half2*)&v2; __half2* h3 = (__half2*)&v3;
#pragma unroll
            for (int i = 0; i < 4; ++i) {
                float2 f0 = __half22float2(h0[i]); float2 f1 = __half22float2(h1[i]);
                float2 f2 = __half22float2(h2[i]); float2 f3 = __half22float2(h3[i]);
                a[2*i]   = fmaf(d0, f0.x, fmaf(d1, f1.x, fmaf(d2, f2.x, fmaf(d3, f3.x, a[2*i]))));
                a[2*i+1] = fmaf(d0, f0.y, fmaf(d1, f1.y, fmaf(d2, f2.y, fmaf(d3, f3.y, a[2*i+1]))));
            }
        }
    }

#pragma unroll
    for (int j = 0; j < 8; ++j) {
        a[j] += __shfl_xor(a[j], 16);
        a[j] += __shfl_xor(a[j], 32);
    }
    if (g == 0) {
        f4 b0 = bias4[li * 2], b1v = bias4[li * 2 + 1];
        float o[8];
#pragma unroll
        for (int u = 0; u < 4; ++u) {
            o[u]     = fmaxf(fmaf(di, a[u],     b0[u]),  0.0f);
            o[4 + u] = fmaxf(fmaf(di, a[4 + u], b1v[u]), 0.0f);
        }
        if (OUT16) {
            f16x8 hv;
#pragma unroll
            for (int u = 0; u < 8; ++u) hv[u] = (_Float16)o[u];
            *(f16x8*)((_Float16*)outp + (size_t)wid * 128 + li * 8) = hv;
        } else {
            f4 o0, o1;
#pragma unroll
            for (int u = 0; u < 4; ++u) { o0[u] = o[u]; o1[u] = o[4 + u]; }
            f4* out4 = (f4*)outp;
            out4[(size_t)wid * 32 + li * 2]     = o0;
            out4[(size_t)wid * 32 + li * 2 + 1] = o1;
        }
    }
}

// ---------- launch ----------
extern "C" void kernel_launch(void* const* d_in, const int* in_sizes, int n_in,
                              void* d_out, int out_size, void* d_ws, size_t ws_size,
                              hipStream_t stream) {
    float*       xbuf = (float*)d_in[0];        // fp32 input; later reused for compact g2
    const int*   ei   = (const int*)d_in[1];
    const float* W1   = (const float*)d_in[2];
    const float* b1   = (const float*)d_in[3];
    const float* W2   = (const float*)d_in[4];
    const float* b2   = (const float*)d_in[5];
    float*       out  = (float*)d_out;

    int N = in_sizes[0] / 128;
    int E = in_sizes[1] / 2;
    const int* row = ei;          // sources (x_j)
    const int* col = ei + E;      // targets (aggregate index)

    int nbuck = (N + 255) >> BSHIFT;   // 196 for N=50000

    auto align256 = [](size_t v) { return (v + 255) & ~(size_t)255; };
    char* ws = (char*)d_ws;
    size_t pos = 0;
    int*      off    = (int*)(ws + pos);      pos += align256((size_t)(N + 1) * 4);
    float*    dinv   = (float*)(ws + pos);    pos += align256((size_t)N * 4);
    int*      csr    = (int*)(ws + pos);      pos += align256((size_t)E * 4);
    int*      gcur   = (int*)(ws + pos);      pos += align256(256 * 4);
    uint32_t* binned = (uint32_t*)(ws + pos); pos += align256((size_t)nbuck * BCAP * 4);
    __half*   Wt1    = (__half*)(ws + pos);   pos += align256(128 * 128 * 2);
    __half*   Wt2    = (__half*)(ws + pos);   pos += align256(128 * 128 * 2);
    // total ~10 MB

    // buffer routing (all compact 256-B fp16 rows, nothing in-place):
    //   g1c   : d_out upper half (written by gemm1, read by agg1)
    //   act16 : d_out lower half (written by agg1, read by gemm2)
    //   g2c   : xbuf             (written by gemm2, read by agg2)
    //   final : d_out full       (written by agg2)
    __half* act16 = (__half*)out;
    __half* g1c   = (__half*)((char*)out + (size_t)N * 256);
    __half* g2c   = (__half*)xbuf;

    int binblocks = (E + 2047) / 2048;
    int gblocks   = (N + 63) / 64;
    int ablocks   = (N + 3) / 4;

    // prep: zero gcur + transpose both W's (replaces memset)
    prep_kernel<<<17, 256, 0, stream>>>(W1, W2, Wt1, Wt2, gcur);
    // fused: gemm1 (graph-independent — dinv deferred to agg) + bin
    gemm_bin_kernel<<<gblocks + binblocks, 256, 0, stream>>>(xbuf, Wt1, g1c, N, gblocks,
                                                             row, col, gcur, binned,
                                                             E, N, nbuck);
    bucket_kernel<<<nbuck, 1024, 0, stream>>>(binned, gcur, off, dinv, csr, N, nbuck);

    // layer 1: act1 = relu(di*(di*h_self + Σ dv*h) + b1) -> fp16 compact (d_out lower)
    agg_f16<1, 0><<<ablocks, 256, 0, stream>>>(g1c, csr, off, dinv, (const f4*)b1, act16, N);
    // layer 2: g2' = fp16(dinv * (act1 @ W2)) -> xbuf (pre-scaled rows)
    gemm2_kernel<<<gblocks, 256, 0, stream>>>(act16, Wt2, dinv, g2c, N);
    // agg2: out = relu(di*(g'_self + Σ g'_e) + b2) — no per-edge dinv gather
    agg_f16<0, 1><<<ablocks, 256, 0, stream>>>(g2c, csr, off, dinv, (const f4*)b2, out, N);
}

// Round 8
// 180.602 us; speedup vs baseline: 1.3188x; 1.0054x over previous
//
#include <hip/hip_runtime.h>
#include <hip/hip_fp16.h>
#include <stdint.h>

typedef float f4 __attribute__((ext_vector_type(4)));
typedef float f32x4 __attribute__((ext_vector_type(4)));
typedef _Float16 f16x8 __attribute__((ext_vector_type(8)));

#define BSHIFT 8
#define BMASK  255
#define BCAP   8192   // edges per 256-node bucket (mean 4096 -> huge headroom)

// ---------- prep: zero gcur + transpose W1/W2 -> fp16 [c][k] (replaces memset) ----------
__global__ __launch_bounds__(256) void prep_kernel(const float* __restrict__ W1,
                                                   const float* __restrict__ W2,
                                                   __half* __restrict__ Wt1,
                                                   __half* __restrict__ Wt2,
                                                   int* __restrict__ gcur) {
    int t = threadIdx.x, b = blockIdx.x;
    if (b == 0) { gcur[t] = 0; return; }
    int wi = (b - 1) >> 3, bi = (b - 1) & 7;
    const f4* w4 = (const f4*)(wi ? W2 : W1);
    _Float16* dst = (_Float16*)(wi ? Wt2 : Wt1);
#pragma unroll
    for (int it = 0; it < 2; ++it) {
        int chunk = bi * 512 + it * 256 + t;      // f4 index into 128x128 W
        f4 v = w4[chunk];
        int k = chunk >> 5, c0 = (chunk << 2) & 127;
#pragma unroll
        for (int u = 0; u < 4; ++u)
            dst[(size_t)(c0 + u) * 128 + k] = (_Float16)v[u];
    }
}

// ---------- stage B (Wt fp16 [c][k]) into swizzled LDS: byte^=((c&7)<<4) ----------
__device__ __forceinline__ void stage_B(_Float16* Bsw, const __half* __restrict__ Wt) {
    int t = threadIdx.x;
    const f4* wsrc = (const f4*)Wt;
#pragma unroll
    for (int i = 0; i < 8; ++i) {
        int cb = i * 256 + t;
        f4 v = wsrc[cb];
        int lin = cb * 16;
        int c = cb >> 4;
        *(f4*)((char*)Bsw + (lin ^ ((c & 7) << 4))) = v;
    }
}

// ---------- gemm1 body: g1c[row] = half(x_f32[row] @ W); A in regs (hi+lo fp16) ----------
// Block = 64 rows x 128 cols, 4 waves. B-only LDS (32 KB). Writes COMPACT 256-B rows
// into d_out's upper half (no aliasing with the xbuf source at all).
__device__ __forceinline__ void gemm1_body(char* smem, int blk,
                                           const float* __restrict__ src,
                                           const __half* __restrict__ Wt,
                                           __half* __restrict__ g16, int nrows) {
    _Float16* Bsw = (_Float16*)smem;   // 32 KB
    stage_B(Bsw, Wt);

    int t = threadIdx.x;
    int w = t >> 6, lane = t & 63;
    int li = lane & 15, hg = lane >> 4;
    int r = blk * 64 + w * 16 + li;
    int rc = r < nrows ? r : nrows - 1;
    const float* xr = src + (size_t)rc * 128;

    // A frags direct from global: row r, k = kk*32 + hg*8 .. +7 ; hi + residual
    f16x8 af[4], al[4];
#pragma unroll
    for (int kk = 0; kk < 4; ++kk) {
        f4 v0 = *(const f4*)(xr + kk * 32 + hg * 8);
        f4 v1 = *(const f4*)(xr + kk * 32 + hg * 8 + 4);
#pragma unroll
        for (int u = 0; u < 4; ++u) {
            float a0 = v0[u]; _Float16 h0 = (_Float16)a0;
            af[kk][u] = h0;     al[kk][u]     = (_Float16)(a0 - (float)h0);
            float a1 = v1[u]; _Float16 h1 = (_Float16)a1;
            af[kk][u + 4] = h1; al[kk][u + 4] = (_Float16)(a1 - (float)h1);
        }
    }
    __syncthreads();   // B ready (A loads overlapped with B staging)

    f32x4 acc[8];
#pragma unroll
    for (int nn = 0; nn < 8; ++nn) acc[nn] = (f32x4)0.0f;
#pragma unroll
    for (int nn = 0; nn < 8; ++nn) {
        int c = nn * 16 + li;
        int cbase = c * 256;
        int sw = (c & 7) << 4;
#pragma unroll
        for (int kk = 0; kk < 4; ++kk) {
            f16x8 bf = *(const f16x8*)((const char*)Bsw + ((cbase + kk * 64 + hg * 16) ^ sw));
            acc[nn] = __builtin_amdgcn_mfma_f32_16x16x32_f16(af[kk], bf, acc[nn], 0, 0, 0);
            acc[nn] = __builtin_amdgcn_mfma_f32_16x16x32_f16(al[kk], bf, acc[nn], 0, 0, 0);
        }
    }

    // epilogue: C/D col = lane&15, row = (lane>>4)*4 + reg (m89); COMPACT 256-B rows
    int gr0 = blk * 64 + w * 16 + (hg << 2);
#pragma unroll
    for (int nn = 0; nn < 8; ++nn) {
        int c = nn * 16 + li;
#pragma unroll
        for (int q = 0; q < 4; ++q) {
            int rr = gr0 + q;
            if (rr < nrows)
                g16[(size_t)rr * 128 + c] = __float2half(acc[nn][q]);
        }
    }
}

// ---------- bin body: 2048 edges/block -> packed (row<<8 | node_in_bucket) ----------
__device__ __forceinline__ void bin_body(char* smem, int bb,
                                         const int* __restrict__ row,
                                         const int* __restrict__ col,
                                         int* __restrict__ gcur,
                                         uint32_t* __restrict__ binned,
                                         int E, int n, int nbuck) {
    int* hist = (int*)smem;
    int* base = (int*)(smem + 1024);
    int t = threadIdx.x;
    hist[t] = 0;
    __syncthreads();
    int e0 = bb * 2048 + t;
    int cc[8]; uint32_t pk[8];
#pragma unroll
    for (int i = 0; i < 8; ++i) {
        int e = e0 + i * 256;
        cc[i] = -1; pk[i] = 0;
        if (e < E) {
            int c = col[e];
            if ((unsigned)c < (unsigned)n) {
                cc[i] = c >> BSHIFT;
                pk[i] = ((uint32_t)row[e] << BSHIFT) | (uint32_t)(c & BMASK);
            }
        }
    }
#pragma unroll
    for (int i = 0; i < 8; ++i)
        if (cc[i] >= 0) atomicAdd(&hist[cc[i]], 1);
    __syncthreads();
    if (t < nbuck) {
        int h = hist[t];
        if (h) base[t] = atomicAdd(&gcur[t], h);
        hist[t] = 0;
    }
    __syncthreads();
#pragma unroll
    for (int i = 0; i < 8; ++i)
        if (cc[i] >= 0) {
            int b = cc[i];
            int p = base[b] + atomicAdd(&hist[b], 1);
            if (p < BCAP) binned[(size_t)b * BCAP + p] = pk[i];
        }
}

// ---------- fused kernel1: gemm1 blocks + bin blocks (disjoint roles, 32 KB LDS) ----------
__global__ __launch_bounds__(256) void gemm_bin_kernel(const float* __restrict__ src,
                                                       const __half* __restrict__ Wt,
                                                       __half* __restrict__ g16,
                                                       int nrows, int gblocks,
                                                       const int* __restrict__ row,
                                                       const int* __restrict__ col,
                                                       int* __restrict__ gcur,
                                                       uint32_t* __restrict__ binned,
                                                       int E, int n, int nbuck) {
    __shared__ char smem[32768];
    if ((int)blockIdx.x < gblocks)
        gemm1_body(smem, blockIdx.x, src, Wt, g16, nrows);
    else
        bin_body(smem, blockIdx.x - gblocks, row, col, gcur, binned, E, n, nbuck);
}

// ---------- gemm2: g2c[row] = half(dinv[row] * (act16[row] @ W)); compact rows ----------
// Pre-scaling by dinv here (graph known by now) removes the per-edge dinv gather in agg2.
__global__ __launch_bounds__(256) void gemm2_kernel(const __half* __restrict__ act16,
                                                    const __half* __restrict__ Wt,
                                                    const float* __restrict__ dinv,
                                                    __half* __restrict__ g16, int nrows) {
    __shared__ char smem[32768];
    _Float16* Bsw = (_Float16*)smem;
    stage_B(Bsw, Wt);

    int t = threadIdx.x;
    int w = t >> 6, lane = t & 63;
    int li = lane & 15, hg = lane >> 4;
    int r = blockIdx.x * 64 + w * 16 + li;
    int rc = r < nrows ? r : nrows - 1;
    const _Float16* xr = (const _Float16*)act16 + (size_t)rc * 128;

    f16x8 af[4];
#pragma unroll
    for (int kk = 0; kk < 4; ++kk)
        af[kk] = *(const f16x8*)(xr + kk * 32 + hg * 8);
    __syncthreads();

    f32x4 acc[8];
#pragma unroll
    for (int nn = 0; nn < 8; ++nn) acc[nn] = (f32x4)0.0f;
#pragma unroll
    for (int nn = 0; nn < 8; ++nn) {
        int c = nn * 16 + li;
        int cbase = c * 256;
        int sw = (c & 7) << 4;
#pragma unroll
        for (int kk = 0; kk < 4; ++kk) {
            f16x8 bf = *(const f16x8*)((const char*)Bsw + ((cbase + kk * 64 + hg * 16) ^ sw));
            acc[nn] = __builtin_amdgcn_mfma_f32_16x16x32_f16(af[kk], bf, acc[nn], 0, 0, 0);
        }
    }

    int gr0 = blockIdx.x * 64 + w * 16 + (hg << 2);
    float dv[4];
#pragma unroll
    for (int q = 0; q < 4; ++q) {
        int rr = gr0 + q;
        dv[q] = dinv[rr < nrows ? rr : 0];
    }
#pragma unroll
    for (int nn = 0; nn < 8; ++nn) {
        int c = nn * 16 + li;
#pragma unroll
        for (int q = 0; q < 4; ++q) {
            int rr = gr0 + q;
            if (rr < nrows)
                g16[(size_t)rr * 128 + c] = __float2half(acc[nn][q] * dv[q]);
        }
    }
}

// ---------- bucket: 1024 threads/block, per 256-node bucket -> off / dinv / csr ----------
__global__ __launch_bounds__(1024) void bucket_kernel(const uint32_t* __restrict__ binned,
                                                      const int* __restrict__ gcur,
                                                      int* __restrict__ off,
                                                      float* __restrict__ dinv,
                                                      int* __restrict__ csr,
                                                      int n, int nbuck) {
    __shared__ int wtot[4];
    __shared__ int sbase[256];
    __shared__ int hist[256];
    __shared__ int cur[256];
    int t = threadIdx.x;
    int lane = t & 63, w = t >> 6;
    int b = blockIdx.x;

    int v = 0, inc = 0;
    if (t < 256) {
        v = (t < nbuck) ? gcur[t] : 0;
        inc = v;
#pragma unroll
        for (int d = 1; d < 64; d <<= 1) { int u = __shfl_up(inc, d); if (lane >= d) inc += u; }
        if (lane == 63) wtot[w] = inc;
    }
    __syncthreads();
    if (t < 256) {
        int wb = 0;
        for (int i = 0; i < w; ++i) wb += wtot[i];
        sbase[t] = wb + inc - v;
    }
    __syncthreads();
    int base_b = sbase[b];
    int c_b    = gcur[b];

    if (t < 256) hist[t] = 0;
    __syncthreads();
    const uint32_t* reg = binned + (size_t)b * BCAP;
    for (int j = t; j < c_b; j += 1024)
        atomicAdd(&hist[reg[j] & BMASK], 1);
    __syncthreads();

    int h = 0, inc2 = 0;
    if (t < 256) {
        h = hist[t];
        inc2 = h;
#pragma unroll
        for (int d = 1; d < 64; d <<= 1) { int u = __shfl_up(inc2, d); if (lane >= d) inc2 += u; }
        if (lane == 63) wtot[w] = inc2;
    }
    __syncthreads();
    if (t < 256) {
        int wb2 = 0;
        for (int i = 0; i < w; ++i) wb2 += wtot[i];
        int lo = wb2 + inc2 - h;
        int node = (b << BSHIFT) + t;
        if (node < n) {
            off[node]  = base_b + lo;
            dinv[node] = rsqrtf((float)(h + 1));   // +1: self-loop
        }
        cur[t] = base_b + lo;
    }
    if (b == nbuck - 1 && t == 0)
        off[n] = sbase[nbuck - 1] + gcur[nbuck - 1];
    __syncthreads();
    for (int j = t; j < c_b; j += 1024) {
        uint32_t pv = reg[j];
        int p = atomicAdd(&cur[pv & BMASK], 1);
        csr[p] = (int)(pv >> BSHIFT);
    }
}

// ---------- aggregation v2: one 16-lane GROUP per node (4 nodes/wave, 16 nodes/block) ----------
// Lane li of group g owns cols 8*li..8*li+7 of node (wid*4+g). Per 16-edge chunk the
// group stages 16 csr entries coalesced, issues all 16 row-gathers back-to-back
// (16 outstanding), then consumes. 4 independent node chains per wave; no cross-lane
// reduction needed at the end. Pad lanes carry weight 0 (idx 0 -> cache-hot row).
// PRE=0: weight = dinv[idx]; out = relu(di*(di*h_self + Σ w_e*h_e) + b)
// PRE=1: weight = 1;          out = relu(di*(g'_self + Σ g'_e) + b)
template<int OUT16, int PRE>
__global__ __launch_bounds__(256) void agg_f16(const __half* __restrict__ gh,
                                               const int* __restrict__ csr,
                                               const int* __restrict__ off,
                                               const float* __restrict__ dinv,
                                               const f4* __restrict__ bias4,    // [32]
                                               void* __restrict__ outp,
                                               int n) {
    int wid  = (blockIdx.x * 256 + threadIdx.x) >> 6;
    int lane = threadIdx.x & 63;
    int g  = lane >> 4;
    int li = lane & 15;
    int gbase = lane & 48;                 // group's lane base for shfl

    int node = wid * 4 + g;
    bool valid = node < n;
    int nodeC = valid ? node : 0;
    float di = dinv[nodeC];

    float a[8];
    {
        f4 sv = ((const f4*)(gh + (size_t)nodeC * 128))[li];   // self row segment
        __half2* sh = (__half2*)&sv;
        float sc = PRE ? 1.0f : di;
#pragma unroll
        for (int i = 0; i < 4; ++i) {
            float2 f = __half22float2(sh[i]);
            a[2*i] = sc * f.x; a[2*i+1] = sc * f.y;
        }
    }

    int s = off[nodeC];
    int deg = valid ? (off[nodeC + 1] - s) : 0;

    for (int base = 0; __any(base < deg); base += 16) {
        int idx = 0; float wv = 0.0f;
        if (base + li < deg) {
            idx = csr[s + base + li];             // group-coalesced (16 entries)
            wv  = PRE ? 1.0f : dinv[idx];
        }
        int rr[16];
#pragma unroll
        for (int t2 = 0; t2 < 16; ++t2) rr[t2] = __shfl(idx, gbase + t2);
        f4 v[16];
#pragma unroll
        for (int t2 = 0; t2 < 16; ++t2)
            v[t2] = ((const f4*)(gh + (size_t)rr[t2] * 128))[li];   // 16 gathers in flight
        if (PRE) {
            int rem = deg - base;                  // group-uniform
#pragma unroll
            for (int t2 = 0; t2 < 16; ++t2) {
                float wt = (t2 < rem) ? 1.0f : 0.0f;
                __half2* hv = (__half2*)&v[t2];
#pragma unroll
                for (int i = 0; i < 4; ++i) {
                    float2 f = __half22float2(hv[i]);
                    a[2*i]   = fmaf(wt, f.x, a[2*i]);
                    a[2*i+1] = fmaf(wt, f.y, a[2*i+1]);
                }
            }
        } else {
#pragma unroll
            for (int t2 = 0; t2 < 16; ++t2) {
                float wt = __shfl(wv, gbase + t2);
                __half2* hv = (__half2*)&v[t2];
#pragma unroll
                for (int i = 0; i < 4; ++i) {
                    float2 f = __half22float2(hv[i]);
                    a[2*i]   = fmaf(wt, f.x, a[2*i]);
                    a[2*i+1] = fmaf(wt, f.y, a[2*i+1]);
                }
            }
        }
    }

    if (valid) {
        f4 b0 = bias4[li * 2], b1v = bias4[li * 2 + 1];
        float o[8];
#pragma unroll
        for (int u = 0; u < 4; ++u) {
            o[u]     = fmaxf(fmaf(di, a[u],     b0[u]),  0.0f);
            o[4 + u] = fmaxf(fmaf(di, a[4 + u], b1v[u]), 0.0f);
        }
        if (OUT16) {
            f16x8 hv;
#pragma unroll
            for (int u = 0; u < 8; ++u) hv[u] = (_Float16)o[u];
            *(f16x8*)((_Float16*)outp + (size_t)node * 128 + li * 8) = hv;
        } else {
            f4 o0, o1;
#pragma unroll
            for (int u = 0; u < 4; ++u) { o0[u] = o[u]; o1[u] = o[4 + u]; }
            f4* out4 = (f4*)outp;
            out4[(size_t)node * 32 + li * 2]     = o0;
            out4[(size_t)node * 32 + li * 2 + 1] = o1;
        }
    }
}

// ---------- launch ----------
extern "C" void kernel_launch(void* const* d_in, const int* in_sizes, int n_in,
                              void* d_out, int out_size, void* d_ws, size_t ws_size,
                              hipStream_t stream) {
    float*       xbuf = (float*)d_in[0];        // fp32 input; later reused for compact g2
    const int*   ei   = (const int*)d_in[1];
    const float* W1   = (const float*)d_in[2];
    const float* b1   = (const float*)d_in[3];
    const float* W2   = (const float*)d_in[4];
    const float* b2   = (const float*)d_in[5];
    float*       out  = (float*)d_out;

    int N = in_sizes[0] / 128;
    int E = in_sizes[1] / 2;
    const int* row = ei;          // sources (x_j)
    const int* col = ei + E;      // targets (aggregate index)

    int nbuck = (N + 255) >> BSHIFT;   // 196 for N=50000

    auto align256 = [](size_t v) { return (v + 255) & ~(size_t)255; };
    char* ws = (char*)d_ws;
    size_t pos = 0;
    int*      off    = (int*)(ws + pos);      pos += align256((size_t)(N + 1) * 4);
    float*    dinv   = (float*)(ws + pos);    pos += align256((size_t)N * 4);
    int*      csr    = (int*)(ws + pos);      pos += align256((size_t)E * 4);
    int*      gcur   = (int*)(ws + pos);      pos += align256(256 * 4);
    uint32_t* binned = (uint32_t*)(ws + pos); pos += align256((size_t)nbuck * BCAP * 4);
    __half*   Wt1    = (__half*)(ws + pos);   pos += align256(128 * 128 * 2);
    __half*   Wt2    = (__half*)(ws + pos);   pos += align256(128 * 128 * 2);
    // total ~10 MB

    // buffer routing (all compact 256-B fp16 rows, nothing in-place):
    //   g1c   : d_out upper half (written by gemm1, read by agg1)
    //   act16 : d_out lower half (written by agg1, read by gemm2)
    //   g2c   : xbuf             (written by gemm2, read by agg2)
    //   final : d_out full       (written by agg2)
    __half* act16 = (__half*)out;
    __half* g1c   = (__half*)((char*)out + (size_t)N * 256);
    __half* g2c   = (__half*)xbuf;

    int binblocks = (E + 2047) / 2048;
    int gblocks   = (N + 63) / 64;
    int ablocks   = (N + 15) / 16;     // 16 nodes per block (group-per-node agg)

    // prep: zero gcur + transpose both W's (replaces memset)
    prep_kernel<<<17, 256, 0, stream>>>(W1, W2, Wt1, Wt2, gcur);
    // fused: gemm1 (graph-independent — dinv deferred to agg) + bin
    gemm_bin_kernel<<<gblocks + binblocks, 256, 0, stream>>>(xbuf, Wt1, g1c, N, gblocks,
                                                             row, col, gcur, binned,
                                                             E, N, nbuck);
    bucket_kernel<<<nbuck, 1024, 0, stream>>>(binned, gcur, off, dinv, csr, N, nbuck);

    // layer 1: act1 = relu(di*(di*h_self + Σ dv*h) + b1) -> fp16 compact (d_out lower)
    agg_f16<1, 0><<<ablocks, 256, 0, stream>>>(g1c, csr, off, dinv, (const f4*)b1, act16, N);
    // layer 2: g2' = fp16(dinv * (act1 @ W2)) -> xbuf (pre-scaled rows)
    gemm2_kernel<<<gblocks, 256, 0, stream>>>(act16, Wt2, dinv, g2c, N);
    // agg2: out = relu(di*(g'_self + Σ g'_e) + b2) — no per-edge dinv gather
    agg_f16<0, 1><<<ablocks, 256, 0, stream>>>(g2c, csr, off, dinv, (const f4*)b2, out, N);
}